// Round 22
// baseline (1344.021 us; speedup 1.0000x reference)
//
#include <hip/hip_runtime.h>
#include <hip/hip_bf16.h>

#define NB 512
#define NL 128
#define NF 900
#define ND 512
#define NE 8
#define LSTR 36                      // LDS row stride (ushorts): 32 data + 4 pad
#define WT_OFF 8192
#define WT_BYTES ((size_t)NE * ND * NF * 4)

typedef short bf16x8 __attribute__((ext_vector_type(8)));
typedef float f32x4 __attribute__((ext_vector_type(4)));

// Output encoding (measured R5-R18; R18/R20/R21 PASSED): harness reads d_out
// as u32 slots, bf16 payload in HIGH u16.
static __device__ __forceinline__ unsigned int enc_bf16_hi(float v) {
    unsigned int u = __float_as_uint(v);
    return (u + 0x7FFFu + ((u >> 16) & 1u)) & 0xFFFF0000u;
}
static __device__ __forceinline__ unsigned short bf16r(float v) {
    unsigned int u = __float_as_uint(v);
    return (unsigned short)((u + 0x7FFFu + ((u >> 16) & 1u)) >> 16);
}
static __device__ __forceinline__ float b2f(unsigned short h) {
    return __uint_as_float(((unsigned int)h) << 16);
}
static __device__ __forceinline__ void split2(float v, unsigned short& hi, unsigned short& lo) {
    hi = bf16r(v); lo = bf16r(v - b2f(hi));
}
static __device__ __forceinline__ bf16x8 read8(const unsigned short* p) {
    union { ushort4 u[2]; bf16x8 v; } r;
    r.u[0] = *(const ushort4*)(p);
    r.u[1] = *(const ushort4*)(p + 4);
    return r.v;
}

// ---------------- H0 gates (verified R18/R20/R21) ----------------
__global__ void gates_kernel(const float* __restrict__ logits,
                             const int* __restrict__ masks,
                             int* __restrict__ eidx,
                             float* __restrict__ gval) {
    int b = blockIdx.x * blockDim.x + threadIdx.x;
    if (b >= NB) return;
    float l[NE], pr[NE], pm[NE];
    int mk[NE];
    float mx = -3.0e38f;
    for (int e = 0; e < NE; ++e) {
        l[e] = logits[b * NE + e];
        mk[e] = masks[b * NE + e];
        mx = fmaxf(mx, l[e]);
    }
    float Z = 0.f;
    for (int e = 0; e < NE; ++e) { pr[e] = expf(l[e] - mx); Z += pr[e]; }
    for (int e = 0; e < NE; ++e) { pr[e] /= Z; pm[e] = (mk[e] == 1) ? pr[e] : 0.f; }
    int i1 = 0;
    for (int e = 1; e < NE; ++e) if (pm[e] > pm[i1]) i1 = e;
    int i2 = (i1 == 0) ? 1 : 0;
    for (int e = 0; e < NE; ++e) if (e != i1 && pm[e] > pm[i2]) i2 = e;
    float v1 = pm[i1], v2 = pm[i2];
    float den = v1 + v2 + 1e-9f;
    eidx[2 * b] = i1; eidx[2 * b + 1] = i2;
    gval[2 * b] = v1 / den; gval[2 * b + 1] = v2 / den;
}

// ---------------- W transpose: Wt[e][d][f] = W[e][f][d] ----------------
__global__ void wt_kernel(const float* __restrict__ W, float* __restrict__ Wt) {
    __shared__ float tile[32][33];
    const int e = blockIdx.z, f0 = blockIdx.x * 32, d0 = blockIdx.y * 32;
    const int tx = threadIdx.x & 31, ty = threadIdx.x >> 5;   // 32 x 8
    const float* Wb = W + (size_t)e * NF * ND;
    float* Tb = Wt + (size_t)e * ND * NF;
#pragma unroll
    for (int i = 0; i < 4; ++i) {
        int f = f0 + ty + 8 * i;
        tile[ty + 8 * i][tx] = (f < NF) ? Wb[(size_t)f * ND + d0 + tx] : 0.f;
    }
    __syncthreads();
#pragma unroll
    for (int i = 0; i < 4; ++i) {
        int d = d0 + ty + 8 * i, f = f0 + tx;
        if (f < NF) Tb[(size_t)d * NF + f] = tile[tx][ty + 8 * i];
    }
}

// ---------------- split-precision MFMA GEMM, single-buffer 2-phase ----------------
// LDS 36.9KB -> 4 blocks/CU (16 waves, 50% occupancy). Per step:
// {write regs->LDS | barrier | issue next global loads | frag-read + 3xMFMA | barrier}
__global__ __launch_bounds__(256, 4)
void moe_mfma3_kernel(const float* __restrict__ x,
                      const float* __restrict__ Wt,
                      const float* __restrict__ bias,
                      const int* __restrict__ eidx,
                      const float* __restrict__ gval,
                      unsigned int* __restrict__ out32) {
    __shared__ unsigned short sxh[128 * LSTR], sxl[128 * LSTR];
    __shared__ unsigned short swh[128 * LSTR], swl[128 * LSTR];

    const int b = blockIdx.y, n0 = blockIdx.x * 128;
    const int t = threadIdx.x, lane = t & 63, wid = t >> 6;
    const int wr = wid >> 1, wc = wid & 1;

    const int e0 = eidx[2 * b], e1 = eidx[2 * b + 1];
    const float g0 = gval[2 * b], g1 = gval[2 * b + 1];

    const float* xb = x + (size_t)b * NL * NF;
    const float* T0 = Wt + (size_t)e0 * ND * NF + (size_t)n0 * NF;
    const float* T1 = Wt + (size_t)e1 * ND * NF + (size_t)n0 * NF;

    const int rowi = t >> 3;     // 0..31 (+32 per p)
    const int k4   = t & 7;

    f32x4 acc[4][4] = {};
    float4 nx[4], nw0[4], nw1[4];

    // prologue: load step 0 into regs (k0=0, all f valid)
#pragma unroll
    for (int p = 0; p < 4; ++p) {
        int row = rowi + 32 * p;
        int f = 4 * k4;
        nx[p]  = *(const float4*)(xb + (size_t)row * NF + f);
        nw0[p] = *(const float4*)(T0 + (size_t)row * NF + f);
        nw1[p] = *(const float4*)(T1 + (size_t)row * NF + f);
    }

    for (int step = 0; step < 29; ++step) {
        // ---- write phase: split regs -> LDS ----
#pragma unroll
        for (int p = 0; p < 4; ++p) {
            int row = rowi + 32 * p;
            ushort4 xh, xl, wh, wl;
            split2(nx[p].x, xh.x, xl.x); split2(nx[p].y, xh.y, xl.y);
            split2(nx[p].z, xh.z, xl.z); split2(nx[p].w, xh.w, xl.w);
            float c0 = g0 * nw0[p].x + g1 * nw1[p].x, c1 = g0 * nw0[p].y + g1 * nw1[p].y;
            float c2 = g0 * nw0[p].z + g1 * nw1[p].z, c3 = g0 * nw0[p].w + g1 * nw1[p].w;
            split2(c0, wh.x, wl.x); split2(c1, wh.y, wl.y);
            split2(c2, wh.z, wl.z); split2(c3, wh.w, wl.w);
            int o = row * LSTR + 4 * k4;
            *(ushort4*)&sxh[o] = xh; *(ushort4*)&sxl[o] = xl;
            *(ushort4*)&swh[o] = wh; *(ushort4*)&swl[o] = wl;
        }
        __syncthreads();

        // ---- issue next-step global loads (latency hides under MFMA phase) ----
        if (step < 28) {
            const int k0n = (step + 1) * 32;
#pragma unroll
            for (int p = 0; p < 4; ++p) {
                int row = rowi + 32 * p;
                int f = k0n + 4 * k4;
                float4 z; z.x = z.y = z.z = z.w = 0.f;
                bool ok = (f < NF);   // NF%4==0: 4-chunks fully in or out
                nx[p]  = ok ? *(const float4*)(xb + (size_t)row * NF + f) : z;
                nw0[p] = ok ? *(const float4*)(T0 + (size_t)row * NF + f) : z;
                nw1[p] = ok ? *(const float4*)(T1 + (size_t)row * NF + f) : z;
            }
        }

        // ---- fragments + 3x MFMA ----
        bf16x8 ah[4], al[4], bh[4], bl[4];
#pragma unroll
        for (int fm = 0; fm < 4; ++fm) {
            int o = (wr * 64 + fm * 16 + (lane & 15)) * LSTR + (lane >> 4) * 8;
            ah[fm] = read8(&sxh[o]); al[fm] = read8(&sxl[o]);
        }
#pragma unroll
        for (int fn = 0; fn < 4; ++fn) {
            int o = (wc * 64 + fn * 16 + (lane & 15)) * LSTR + (lane >> 4) * 8;
            bh[fn] = read8(&swh[o]); bl[fn] = read8(&swl[o]);
        }
#pragma unroll
        for (int fm = 0; fm < 4; ++fm)
#pragma unroll
            for (int fn = 0; fn < 4; ++fn) {
                acc[fm][fn] = __builtin_amdgcn_mfma_f32_16x16x32_bf16(ah[fm], bh[fn], acc[fm][fn], 0, 0, 0);
                acc[fm][fn] = __builtin_amdgcn_mfma_f32_16x16x32_bf16(ah[fm], bl[fn], acc[fm][fn], 0, 0, 0);
                acc[fm][fn] = __builtin_amdgcn_mfma_f32_16x16x32_bf16(al[fm], bh[fn], acc[fm][fn], 0, 0, 0);
            }
        __syncthreads();
    }

    // epilogue (layout verified R18/R20/R21): D col=lane&15, row=(lane>>4)*4+j
#pragma unroll
    for (int fn = 0; fn < 4; ++fn) {
        int col = n0 + wc * 64 + fn * 16 + (lane & 15);
        float bc = g0 * bias[e0 * ND + col] + g1 * bias[e1 * ND + col];
#pragma unroll
        for (int fm = 0; fm < 4; ++fm) {
            int rbase = wr * 64 + fm * 16 + (lane >> 4) * 4;
#pragma unroll
            for (int j = 0; j < 4; ++j)
                out32[((size_t)b * NL + rbase + j) * ND + col] = enc_bf16_hi(acc[fm][fn][j] + bc);
        }
    }
}

// ---------------- fallback (R20 kernel) for small ws ----------------
__global__ __launch_bounds__(256)
void moe_mfma_fb_kernel(const float* __restrict__ x, const float* __restrict__ W,
                        const float* __restrict__ bias, const int* __restrict__ eidx,
                        const float* __restrict__ gval, unsigned int* __restrict__ out32) {
    __shared__ unsigned short xh[128 * 40], xl[128 * 40];
    __shared__ unsigned short wh[128 * 40], wl[128 * 40];
    const int b = blockIdx.y, n0 = blockIdx.x * 128;
    const int t = threadIdx.x, lane = t & 63, wid = t >> 6;
    const int wr = wid >> 1, wc = wid & 1;
    const int e0 = eidx[2 * b], e1 = eidx[2 * b + 1];
    const float g0 = gval[2 * b], g1 = gval[2 * b + 1];
    const float* xb = x + (size_t)b * NL * NF;
    const float* W0 = W + (size_t)e0 * NF * ND + n0;
    const float* W1 = W + (size_t)e1 * NF * ND + n0;
    f32x4 acc[4][4] = {};
    for (int k0 = 0; k0 < 928; k0 += 32) {
#pragma unroll
        for (int p = 0; p < 4; ++p) {
            int idx = t + 256 * p, row = idx >> 3, c4 = idx & 7, f = k0 + 4 * c4;
            float4 v; v.x = v.y = v.z = v.w = 0.f;
            if (f + 3 < NF) v = *(const float4*)(xb + (size_t)row * NF + f);
            ushort4 h, lo;
            split2(v.x, h.x, lo.x); split2(v.y, h.y, lo.y);
            split2(v.z, h.z, lo.z); split2(v.w, h.w, lo.w);
            *(ushort4*)&xh[row * 40 + 4 * c4] = h; *(ushort4*)&xl[row * 40 + 4 * c4] = lo;
        }
#pragma unroll
        for (int p = 0; p < 8; ++p) {
            int idx = t + 256 * p, c = idx & 127, kp = idx >> 7, f = k0 + 2 * kp;
            float u0 = 0.f, u1 = 0.f;
            if (f < NF)     u0 = g0 * W0[(size_t)f * ND + c] + g1 * W1[(size_t)f * ND + c];
            if (f + 1 < NF) u1 = g0 * W0[(size_t)(f + 1) * ND + c] + g1 * W1[(size_t)(f + 1) * ND + c];
            unsigned short h0, l0, h1, l1;
            split2(u0, h0, l0); split2(u1, h1, l1);
            *(unsigned int*)&wh[c * 40 + 2 * kp] = (unsigned int)h0 | ((unsigned int)h1 << 16);
            *(unsigned int*)&wl[c * 40 + 2 * kp] = (unsigned int)l0 | ((unsigned int)l1 << 16);
        }
        __syncthreads();
        bf16x8 ah[4], al[4], bh[4], bl[4];
#pragma unroll
        for (int fm = 0; fm < 4; ++fm) {
            int off = (wr * 64 + fm * 16 + (lane & 15)) * 40 + (lane >> 4) * 8;
            ah[fm] = *(const bf16x8*)&xh[off]; al[fm] = *(const bf16x8*)&xl[off];
        }
#pragma unroll
        for (int fn = 0; fn < 4; ++fn) {
            int off = (wc * 64 + fn * 16 + (lane & 15)) * 40 + (lane >> 4) * 8;
            bh[fn] = *(const bf16x8*)&wh[off]; bl[fn] = *(const bf16x8*)&wl[off];
        }
#pragma unroll
        for (int fm = 0; fm < 4; ++fm)
#pragma unroll
            for (int fn = 0; fn < 4; ++fn) {
                acc[fm][fn] = __builtin_amdgcn_mfma_f32_16x16x32_bf16(ah[fm], bh[fn], acc[fm][fn], 0, 0, 0);
                acc[fm][fn] = __builtin_amdgcn_mfma_f32_16x16x32_bf16(ah[fm], bl[fn], acc[fm][fn], 0, 0, 0);
                acc[fm][fn] = __builtin_amdgcn_mfma_f32_16x16x32_bf16(al[fm], bh[fn], acc[fm][fn], 0, 0, 0);
            }
        __syncthreads();
    }
#pragma unroll
    for (int fn = 0; fn < 4; ++fn) {
        int col = n0 + wc * 64 + fn * 16 + (lane & 15);
        float bc = g0 * bias[e0 * ND + col] + g1 * bias[e1 * ND + col];
#pragma unroll
        for (int fm = 0; fm < 4; ++fm) {
            int rbase = wr * 64 + fm * 16 + (lane >> 4) * 4;
#pragma unroll
            for (int j = 0; j < 4; ++j)
                out32[((size_t)b * NL + rbase + j) * ND + col] = enc_bf16_hi(acc[fm][fn][j] + bc);
        }
    }
}

extern "C" void kernel_launch(void* const* d_in, const int* in_sizes, int n_in,
                              void* d_out, int out_size, void* d_ws, size_t ws_size,
                              hipStream_t stream) {
    const float* x      = (const float*)d_in[0];
    const float* logits = (const float*)d_in[1];
    const int*   masks  = (const int*)d_in[2];
    const float* W      = (const float*)d_in[3];
    const float* bias   = (const float*)d_in[4];
    unsigned int* out32 = (unsigned int*)d_out;

    int*   eidx = (int*)d_ws;
    float* gval = (float*)((char*)d_ws + 4096);

    gates_kernel<<<dim3(2), dim3(256), 0, stream>>>(logits, masks, eidx, gval);

    if (ws_size >= WT_OFF + WT_BYTES) {
        float* Wt = (float*)((char*)d_ws + WT_OFF);
        wt_kernel<<<dim3(29, 16, 8), dim3(256), 0, stream>>>(W, Wt);
        moe_mfma3_kernel<<<dim3(ND / 128, NB), dim3(256), 0, stream>>>(
            x, Wt, bias, eidx, gval, out32);
    } else {
        moe_mfma_fb_kernel<<<dim3(ND / 128, NB), dim3(256), 0, stream>>>(
            x, W, bias, eidx, gval, out32);
    }
}

// Round 23
// 611.305 us; speedup vs baseline: 2.1986x; 2.1986x over previous
//
#include <hip/hip_runtime.h>
#include <hip/hip_bf16.h>

#define NB 512
#define NL 128
#define NF 900
#define ND 512
#define NE 8
#define LSTR 36                      // LDS row stride (ushorts): 32 data + 4 pad
#define WT_OFF 8192
#define WT_BYTES ((size_t)NE * ND * NF * 4)

typedef short bf16x8 __attribute__((ext_vector_type(8)));
typedef float f32x4 __attribute__((ext_vector_type(4)));

// Output encoding (measured R5-R18; R18/R20/R21/R22 PASSED): harness reads
// d_out as u32 slots, bf16 payload in HIGH u16.
static __device__ __forceinline__ unsigned int enc_bf16_hi(float v) {
    unsigned int u = __float_as_uint(v);
    return (u + 0x7FFFu + ((u >> 16) & 1u)) & 0xFFFF0000u;
}
static __device__ __forceinline__ unsigned short bf16r(float v) {
    unsigned int u = __float_as_uint(v);
    return (unsigned short)((u + 0x7FFFu + ((u >> 16) & 1u)) >> 16);
}
static __device__ __forceinline__ float b2f(unsigned short h) {
    return __uint_as_float(((unsigned int)h) << 16);
}
static __device__ __forceinline__ void split2(float v, unsigned short& hi, unsigned short& lo) {
    hi = bf16r(v); lo = bf16r(v - b2f(hi));
}
static __device__ __forceinline__ bf16x8 read8(const unsigned short* p) {
    union { ushort4 u[2]; bf16x8 v; } r;
    r.u[0] = *(const ushort4*)(p);
    r.u[1] = *(const ushort4*)(p + 4);
    return r.v;
}

// ---------------- H0 gates (verified) ----------------
__global__ void gates_kernel(const float* __restrict__ logits,
                             const int* __restrict__ masks,
                             int* __restrict__ eidx,
                             float* __restrict__ gval) {
    int b = blockIdx.x * blockDim.x + threadIdx.x;
    if (b >= NB) return;
    float l[NE], pr[NE], pm[NE];
    int mk[NE];
    float mx = -3.0e38f;
    for (int e = 0; e < NE; ++e) {
        l[e] = logits[b * NE + e];
        mk[e] = masks[b * NE + e];
        mx = fmaxf(mx, l[e]);
    }
    float Z = 0.f;
    for (int e = 0; e < NE; ++e) { pr[e] = expf(l[e] - mx); Z += pr[e]; }
    for (int e = 0; e < NE; ++e) { pr[e] /= Z; pm[e] = (mk[e] == 1) ? pr[e] : 0.f; }
    int i1 = 0;
    for (int e = 1; e < NE; ++e) if (pm[e] > pm[i1]) i1 = e;
    int i2 = (i1 == 0) ? 1 : 0;
    for (int e = 0; e < NE; ++e) if (e != i1 && pm[e] > pm[i2]) i2 = e;
    float v1 = pm[i1], v2 = pm[i2];
    float den = v1 + v2 + 1e-9f;
    eidx[2 * b] = i1; eidx[2 * b + 1] = i2;
    gval[2 * b] = v1 / den; gval[2 * b + 1] = v2 / den;
}

// ---------------- W transpose: Wt[e][d][f] = W[e][f][d] ----------------
__global__ void wt_kernel(const float* __restrict__ W, float* __restrict__ Wt) {
    __shared__ float tile[32][33];
    const int e = blockIdx.z, f0 = blockIdx.x * 32, d0 = blockIdx.y * 32;
    const int tx = threadIdx.x & 31, ty = threadIdx.x >> 5;   // 32 x 8
    const float* Wb = W + (size_t)e * NF * ND;
    float* Tb = Wt + (size_t)e * ND * NF;
#pragma unroll
    for (int i = 0; i < 4; ++i) {
        int f = f0 + ty + 8 * i;
        tile[ty + 8 * i][tx] = (f < NF) ? Wb[(size_t)f * ND + d0 + tx] : 0.f;
    }
    __syncthreads();
#pragma unroll
    for (int i = 0; i < 4; ++i) {
        int d = d0 + ty + 8 * i, f = f0 + tx;
        if (f < NF) Tb[(size_t)d * NF + f] = tile[tx][ty + 8 * i];
    }
}

// ---------------- split-precision MFMA GEMM, single-buffer, 3 blocks/CU ----------------
// XCD-colocating swizzle: lin -> {xcd=lin%8, n=(lin/8)%4, b=xcd+8*(lin/32)}:
// all 4 n-tiles of a batch dispatch consecutively on ONE XCD -> x L2 reuse.
__global__ __launch_bounds__(256, 3)
void moe_mfma4_kernel(const float* __restrict__ x,
                      const float* __restrict__ Wt,
                      const float* __restrict__ bias,
                      const int* __restrict__ eidx,
                      const float* __restrict__ gval,
                      unsigned int* __restrict__ out32) {
    __shared__ unsigned short sxh[128 * LSTR], sxl[128 * LSTR];
    __shared__ unsigned short swh[128 * LSTR], swl[128 * LSTR];

    const int lin = blockIdx.x;
    const int b   = (lin & 7) + 8 * (lin >> 5);
    const int n0  = ((lin >> 3) & 3) * 128;
    const int t = threadIdx.x, lane = t & 63, wid = t >> 6;
    const int wr = wid >> 1, wc = wid & 1;

    const int e0 = eidx[2 * b], e1 = eidx[2 * b + 1];
    const float g0 = gval[2 * b], g1 = gval[2 * b + 1];

    const float* xb = x + (size_t)b * NL * NF;
    const float* T0 = Wt + (size_t)e0 * ND * NF + (size_t)n0 * NF;
    const float* T1 = Wt + (size_t)e1 * ND * NF + (size_t)n0 * NF;

    const int rowi = t >> 3;     // 0..31 (+32 per p)
    const int k4   = t & 7;

    f32x4 acc[4][4] = {};
    float4 nx[4], nw0[4], nw1[4];

    // prologue: load step 0 into regs (k0=0, all f valid)
#pragma unroll
    for (int p = 0; p < 4; ++p) {
        int row = rowi + 32 * p;
        int f = 4 * k4;
        nx[p]  = *(const float4*)(xb + (size_t)row * NF + f);
        nw0[p] = *(const float4*)(T0 + (size_t)row * NF + f);
        nw1[p] = *(const float4*)(T1 + (size_t)row * NF + f);
    }

    for (int step = 0; step < 29; ++step) {
        // ---- write phase: split regs -> LDS ----
#pragma unroll
        for (int p = 0; p < 4; ++p) {
            int row = rowi + 32 * p;
            ushort4 xh, xl, wh, wl;
            split2(nx[p].x, xh.x, xl.x); split2(nx[p].y, xh.y, xl.y);
            split2(nx[p].z, xh.z, xl.z); split2(nx[p].w, xh.w, xl.w);
            float c0 = g0 * nw0[p].x + g1 * nw1[p].x, c1 = g0 * nw0[p].y + g1 * nw1[p].y;
            float c2 = g0 * nw0[p].z + g1 * nw1[p].z, c3 = g0 * nw0[p].w + g1 * nw1[p].w;
            split2(c0, wh.x, wl.x); split2(c1, wh.y, wl.y);
            split2(c2, wh.z, wl.z); split2(c3, wh.w, wl.w);
            int o = row * LSTR + 4 * k4;
            *(ushort4*)&sxh[o] = xh; *(ushort4*)&sxl[o] = xl;
            *(ushort4*)&swh[o] = wh; *(ushort4*)&swl[o] = wl;
        }
        __syncthreads();

        // ---- issue next-step global loads (hide under MFMA phase) ----
        if (step < 28) {
            const int k0n = (step + 1) * 32;
#pragma unroll
            for (int p = 0; p < 4; ++p) {
                int row = rowi + 32 * p;
                int f = k0n + 4 * k4;
                float4 z; z.x = z.y = z.z = z.w = 0.f;
                bool ok = (f < NF);   // NF%4==0: 4-chunks fully in or out
                nx[p]  = ok ? *(const float4*)(xb + (size_t)row * NF + f) : z;
                nw0[p] = ok ? *(const float4*)(T0 + (size_t)row * NF + f) : z;
                nw1[p] = ok ? *(const float4*)(T1 + (size_t)row * NF + f) : z;
            }
        }

        // ---- fragments + 3x MFMA ----
        bf16x8 ah[4], al[4], bh[4], bl[4];
#pragma unroll
        for (int fm = 0; fm < 4; ++fm) {
            int o = (wr * 64 + fm * 16 + (lane & 15)) * LSTR + (lane >> 4) * 8;
            ah[fm] = read8(&sxh[o]); al[fm] = read8(&sxl[o]);
        }
#pragma unroll
        for (int fn = 0; fn < 4; ++fn) {
            int o = (wc * 64 + fn * 16 + (lane & 15)) * LSTR + (lane >> 4) * 8;
            bh[fn] = read8(&swh[o]); bl[fn] = read8(&swl[o]);
        }
#pragma unroll
        for (int fm = 0; fm < 4; ++fm)
#pragma unroll
            for (int fn = 0; fn < 4; ++fn) {
                acc[fm][fn] = __builtin_amdgcn_mfma_f32_16x16x32_bf16(ah[fm], bh[fn], acc[fm][fn], 0, 0, 0);
                acc[fm][fn] = __builtin_amdgcn_mfma_f32_16x16x32_bf16(ah[fm], bl[fn], acc[fm][fn], 0, 0, 0);
                acc[fm][fn] = __builtin_amdgcn_mfma_f32_16x16x32_bf16(al[fm], bh[fn], acc[fm][fn], 0, 0, 0);
            }
        __syncthreads();
    }

    // epilogue (layout verified): D col=lane&15, row=(lane>>4)*4+j
#pragma unroll
    for (int fn = 0; fn < 4; ++fn) {
        int col = n0 + wc * 64 + fn * 16 + (lane & 15);
        float bc = g0 * bias[e0 * ND + col] + g1 * bias[e1 * ND + col];
#pragma unroll
        for (int fm = 0; fm < 4; ++fm) {
            int rbase = wr * 64 + fm * 16 + (lane >> 4) * 4;
#pragma unroll
            for (int j = 0; j < 4; ++j)
                out32[((size_t)b * NL + rbase + j) * ND + col] = enc_bf16_hi(acc[fm][fn][j] + bc);
        }
    }
}

// ---------------- fallback (R20 kernel) for small ws ----------------
__global__ __launch_bounds__(256)
void moe_mfma_fb_kernel(const float* __restrict__ x, const float* __restrict__ W,
                        const float* __restrict__ bias, const int* __restrict__ eidx,
                        const float* __restrict__ gval, unsigned int* __restrict__ out32) {
    __shared__ unsigned short xh[128 * 40], xl[128 * 40];
    __shared__ unsigned short wh[128 * 40], wl[128 * 40];
    const int b = blockIdx.y, n0 = blockIdx.x * 128;
    const int t = threadIdx.x, lane = t & 63, wid = t >> 6;
    const int wr = wid >> 1, wc = wid & 1;
    const int e0 = eidx[2 * b], e1 = eidx[2 * b + 1];
    const float g0 = gval[2 * b], g1 = gval[2 * b + 1];
    const float* xb = x + (size_t)b * NL * NF;
    const float* W0 = W + (size_t)e0 * NF * ND + n0;
    const float* W1 = W + (size_t)e1 * NF * ND + n0;
    f32x4 acc[4][4] = {};
    for (int k0 = 0; k0 < 928; k0 += 32) {
#pragma unroll
        for (int p = 0; p < 4; ++p) {
            int idx = t + 256 * p, row = idx >> 3, c4 = idx & 7, f = k0 + 4 * c4;
            float4 v; v.x = v.y = v.z = v.w = 0.f;
            if (f + 3 < NF) v = *(const float4*)(xb + (size_t)row * NF + f);
            ushort4 h, lo;
            split2(v.x, h.x, lo.x); split2(v.y, h.y, lo.y);
            split2(v.z, h.z, lo.z); split2(v.w, h.w, lo.w);
            *(ushort4*)&xh[row * 40 + 4 * c4] = h; *(ushort4*)&xl[row * 40 + 4 * c4] = lo;
        }
#pragma unroll
        for (int p = 0; p < 8; ++p) {
            int idx = t + 256 * p, c = idx & 127, kp = idx >> 7, f = k0 + 2 * kp;
            float u0 = 0.f, u1 = 0.f;
            if (f < NF)     u0 = g0 * W0[(size_t)f * ND + c] + g1 * W1[(size_t)f * ND + c];
            if (f + 1 < NF) u1 = g0 * W0[(size_t)(f + 1) * ND + c] + g1 * W1[(size_t)(f + 1) * ND + c];
            unsigned short h0, l0, h1, l1;
            split2(u0, h0, l0); split2(u1, h1, l1);
            *(unsigned int*)&wh[c * 40 + 2 * kp] = (unsigned int)h0 | ((unsigned int)h1 << 16);
            *(unsigned int*)&wl[c * 40 + 2 * kp] = (unsigned int)l0 | ((unsigned int)l1 << 16);
        }
        __syncthreads();
        bf16x8 ah[4], al[4], bh[4], bl[4];
#pragma unroll
        for (int fm = 0; fm < 4; ++fm) {
            int off = (wr * 64 + fm * 16 + (lane & 15)) * 40 + (lane >> 4) * 8;
            ah[fm] = *(const bf16x8*)&xh[off]; al[fm] = *(const bf16x8*)&xl[off];
        }
#pragma unroll
        for (int fn = 0; fn < 4; ++fn) {
            int off = (wc * 64 + fn * 16 + (lane & 15)) * 40 + (lane >> 4) * 8;
            bh[fn] = *(const bf16x8*)&wh[off]; bl[fn] = *(const bf16x8*)&wl[off];
        }
#pragma unroll
        for (int fm = 0; fm < 4; ++fm)
#pragma unroll
            for (int fn = 0; fn < 4; ++fn) {
                acc[fm][fn] = __builtin_amdgcn_mfma_f32_16x16x32_bf16(ah[fm], bh[fn], acc[fm][fn], 0, 0, 0);
                acc[fm][fn] = __builtin_amdgcn_mfma_f32_16x16x32_bf16(ah[fm], bl[fn], acc[fm][fn], 0, 0, 0);
                acc[fm][fn] = __builtin_amdgcn_mfma_f32_16x16x32_bf16(al[fm], bh[fn], acc[fm][fn], 0, 0, 0);
            }
        __syncthreads();
    }
#pragma unroll
    for (int fn = 0; fn < 4; ++fn) {
        int col = n0 + wc * 64 + fn * 16 + (lane & 15);
        float bc = g0 * bias[e0 * ND + col] + g1 * bias[e1 * ND + col];
#pragma unroll
        for (int fm = 0; fm < 4; ++fm) {
            int rbase = wr * 64 + fm * 16 + (lane >> 4) * 4;
#pragma unroll
            for (int j = 0; j < 4; ++j)
                out32[((size_t)b * NL + rbase + j) * ND + col] = enc_bf16_hi(acc[fm][fn][j] + bc);
        }
    }
}

extern "C" void kernel_launch(void* const* d_in, const int* in_sizes, int n_in,
                              void* d_out, int out_size, void* d_ws, size_t ws_size,
                              hipStream_t stream) {
    const float* x      = (const float*)d_in[0];
    const float* logits = (const float*)d_in[1];
    const int*   masks  = (const int*)d_in[2];
    const float* W      = (const float*)d_in[3];
    const float* bias   = (const float*)d_in[4];
    unsigned int* out32 = (unsigned int*)d_out;

    int*   eidx = (int*)d_ws;
    float* gval = (float*)((char*)d_ws + 4096);

    gates_kernel<<<dim3(2), dim3(256), 0, stream>>>(logits, masks, eidx, gval);

    if (ws_size >= WT_OFF + WT_BYTES) {
        float* Wt = (float*)((char*)d_ws + WT_OFF);
        wt_kernel<<<dim3(29, 16, 8), dim3(256), 0, stream>>>(W, Wt);
        moe_mfma4_kernel<<<dim3(NB * 4), dim3(256), 0, stream>>>(
            x, Wt, bias, eidx, gval, out32);
    } else {
        moe_mfma_fb_kernel<<<dim3(ND / 128, NB), dim3(256), 0, stream>>>(
            x, W, bias, eidx, gval, out32);
    }
}

// Round 24
// 507.542 us; speedup vs baseline: 2.6481x; 1.2044x over previous
//
#include <hip/hip_runtime.h>
#include <hip/hip_bf16.h>

#define NB 512
#define NL 128
#define NF 900
#define ND 512
#define NE 8
#define LSTR 36                      // LDS row stride (ushorts): 32 data + 4 pad
#define WT_OFF 8192
#define WT_BYTES ((size_t)NE * ND * NF * 4)

typedef _Float16 f16x8 __attribute__((ext_vector_type(8)));
typedef short bf16x8 __attribute__((ext_vector_type(8)));
typedef float f32x4 __attribute__((ext_vector_type(4)));

// Output encoding (measured R5-R18; R18/R20-R23 PASSED): harness reads d_out
// as u32 slots, bf16 payload in HIGH u16.
static __device__ __forceinline__ unsigned int enc_bf16_hi(float v) {
    unsigned int u = __float_as_uint(v);
    return (u + 0x7FFFu + ((u >> 16) & 1u)) & 0xFFFF0000u;
}
static __device__ __forceinline__ unsigned short bf16r(float v) {
    unsigned int u = __float_as_uint(v);
    return (unsigned short)((u + 0x7FFFu + ((u >> 16) & 1u)) >> 16);
}
static __device__ __forceinline__ float b2f(unsigned short h) {
    return __uint_as_float(((unsigned int)h) << 16);
}
static __device__ __forceinline__ void split2(float v, unsigned short& hi, unsigned short& lo) {
    hi = bf16r(v); lo = bf16r(v - b2f(hi));
}
static __device__ __forceinline__ unsigned short f16b(float v) {
    _Float16 h = (_Float16)v;                      // v_cvt_f16_f32, RNE
    return __builtin_bit_cast(unsigned short, h);
}
static __device__ __forceinline__ f16x8 read8h(const unsigned short* p) {
    union { ushort4 u[2]; f16x8 v; } r;
    r.u[0] = *(const ushort4*)(p);
    r.u[1] = *(const ushort4*)(p + 4);
    return r.v;
}
static __device__ __forceinline__ bf16x8 read8b(const unsigned short* p) {
    union { ushort4 u[2]; bf16x8 v; } r;
    r.u[0] = *(const ushort4*)(p);
    r.u[1] = *(const ushort4*)(p + 4);
    return r.v;
}

// ---------------- H0 gates (verified) ----------------
__global__ void gates_kernel(const float* __restrict__ logits,
                             const int* __restrict__ masks,
                             int* __restrict__ eidx,
                             float* __restrict__ gval) {
    int b = blockIdx.x * blockDim.x + threadIdx.x;
    if (b >= NB) return;
    float l[NE], pr[NE], pm[NE];
    int mk[NE];
    float mx = -3.0e38f;
    for (int e = 0; e < NE; ++e) {
        l[e] = logits[b * NE + e];
        mk[e] = masks[b * NE + e];
        mx = fmaxf(mx, l[e]);
    }
    float Z = 0.f;
    for (int e = 0; e < NE; ++e) { pr[e] = expf(l[e] - mx); Z += pr[e]; }
    for (int e = 0; e < NE; ++e) { pr[e] /= Z; pm[e] = (mk[e] == 1) ? pr[e] : 0.f; }
    int i1 = 0;
    for (int e = 1; e < NE; ++e) if (pm[e] > pm[i1]) i1 = e;
    int i2 = (i1 == 0) ? 1 : 0;
    for (int e = 0; e < NE; ++e) if (e != i1 && pm[e] > pm[i2]) i2 = e;
    float v1 = pm[i1], v2 = pm[i2];
    float den = v1 + v2 + 1e-9f;
    eidx[2 * b] = i1; eidx[2 * b + 1] = i2;
    gval[2 * b] = v1 / den; gval[2 * b + 1] = v2 / den;
}

// ---------------- W transpose: Wt[e][d][f] = W[e][f][d] ----------------
__global__ void wt_kernel(const float* __restrict__ W, float* __restrict__ Wt) {
    __shared__ float tile[32][33];
    const int e = blockIdx.z, f0 = blockIdx.x * 32, d0 = blockIdx.y * 32;
    const int tx = threadIdx.x & 31, ty = threadIdx.x >> 5;   // 32 x 8
    const float* Wb = W + (size_t)e * NF * ND;
    float* Tb = Wt + (size_t)e * ND * NF;
#pragma unroll
    for (int i = 0; i < 4; ++i) {
        int f = f0 + ty + 8 * i;
        tile[ty + 8 * i][tx] = (f < NF) ? Wb[(size_t)f * ND + d0 + tx] : 0.f;
    }
    __syncthreads();
#pragma unroll
    for (int i = 0; i < 4; ++i) {
        int d = d0 + ty + 8 * i, f = f0 + tx;
        if (f < NF) Tb[(size_t)d * NF + f] = tile[tx][ty + 8 * i];
    }
}

// ---------------- single-fp16 MFMA GEMM, double-buffered (R21 structure) ----------------
// Error budget: worst-case input-rounding |err| <= sum|x.w| * 2^-10 ~ 0.012,
// well under the 0.102 threshold on top of the 0.0156 output floor.
// LDS = 2 arrays x 2 bufs x 9.2KB = 36.9KB. One barrier per K-step.
__global__ __launch_bounds__(256, 3)
void moe_mfma_h_kernel(const float* __restrict__ x,
                       const float* __restrict__ Wt,
                       const float* __restrict__ bias,
                       const int* __restrict__ eidx,
                       const float* __restrict__ gval,
                       unsigned int* __restrict__ out32) {
    __shared__ unsigned short sx[2][128 * LSTR];
    __shared__ unsigned short sw[2][128 * LSTR];

    const int b = blockIdx.y, n0 = blockIdx.x * 128;
    const int t = threadIdx.x, lane = t & 63, wid = t >> 6;
    const int wr = wid >> 1, wc = wid & 1;

    const int e0 = eidx[2 * b], e1 = eidx[2 * b + 1];
    const float g0 = gval[2 * b], g1 = gval[2 * b + 1];

    const float* xb = x + (size_t)b * NL * NF;
    const float* T0 = Wt + (size_t)e0 * ND * NF + (size_t)n0 * NF;
    const float* T1 = Wt + (size_t)e1 * ND * NF + (size_t)n0 * NF;

    const int rowi = t >> 3;     // 0..31 (+32 per p)
    const int k4   = t & 7;

    f32x4 acc[4][4] = {};

    // prologue: stage step 0 into buf 0 (k0=0, all f valid)
#pragma unroll
    for (int p = 0; p < 4; ++p) {
        int row = rowi + 32 * p;
        int f = 4 * k4;
        float4 xv = *(const float4*)(xb + (size_t)row * NF + f);
        float4 w0 = *(const float4*)(T0 + (size_t)row * NF + f);
        float4 w1 = *(const float4*)(T1 + (size_t)row * NF + f);
        ushort4 hx, hw;
        hx.x = f16b(xv.x); hx.y = f16b(xv.y); hx.z = f16b(xv.z); hx.w = f16b(xv.w);
        hw.x = f16b(g0 * w0.x + g1 * w1.x); hw.y = f16b(g0 * w0.y + g1 * w1.y);
        hw.z = f16b(g0 * w0.z + g1 * w1.z); hw.w = f16b(g0 * w0.w + g1 * w1.w);
        int o = row * LSTR + 4 * k4;
        *(ushort4*)&sx[0][o] = hx;
        *(ushort4*)&sw[0][o] = hw;
    }

    int cur = 0;
    for (int step = 0; step < 29; ++step) {
        __syncthreads();
        // issue next-step global loads (latency hides under frag reads + MFMA)
        float4 nx[4], nw0[4], nw1[4];
        if (step < 28) {
            const int k0n = (step + 1) * 32;
#pragma unroll
            for (int p = 0; p < 4; ++p) {
                int row = rowi + 32 * p;
                int f = k0n + 4 * k4;
                float4 z; z.x = z.y = z.z = z.w = 0.f;
                bool ok = (f < NF);   // NF%4==0: chunks fully in or out
                nx[p]  = ok ? *(const float4*)(xb + (size_t)row * NF + f) : z;
                nw0[p] = ok ? *(const float4*)(T0 + (size_t)row * NF + f) : z;
                nw1[p] = ok ? *(const float4*)(T1 + (size_t)row * NF + f) : z;
            }
        }
        // fragments + 16 MFMA on cur
        f16x8 af[4], bf[4];
#pragma unroll
        for (int fm = 0; fm < 4; ++fm) {
            int o = (wr * 64 + fm * 16 + (lane & 15)) * LSTR + (lane >> 4) * 8;
            af[fm] = read8h(&sx[cur][o]);
        }
#pragma unroll
        for (int fn = 0; fn < 4; ++fn) {
            int o = (wc * 64 + fn * 16 + (lane & 15)) * LSTR + (lane >> 4) * 8;
            bf[fn] = read8h(&sw[cur][o]);
        }
#pragma unroll
        for (int fm = 0; fm < 4; ++fm)
#pragma unroll
            for (int fn = 0; fn < 4; ++fn)
                acc[fm][fn] = __builtin_amdgcn_mfma_f32_16x16x32_f16(
                    af[fm], bf[fn], acc[fm][fn], 0, 0, 0);
        // convert + write next buffer (disjoint buffer: no barrier needed here)
        if (step < 28) {
            int nxt = cur ^ 1;
#pragma unroll
            for (int p = 0; p < 4; ++p) {
                int row = rowi + 32 * p;
                ushort4 hx, hw;
                hx.x = f16b(nx[p].x); hx.y = f16b(nx[p].y);
                hx.z = f16b(nx[p].z); hx.w = f16b(nx[p].w);
                hw.x = f16b(g0 * nw0[p].x + g1 * nw1[p].x);
                hw.y = f16b(g0 * nw0[p].y + g1 * nw1[p].y);
                hw.z = f16b(g0 * nw0[p].z + g1 * nw1[p].z);
                hw.w = f16b(g0 * nw0[p].w + g1 * nw1[p].w);
                int o = row * LSTR + 4 * k4;
                *(ushort4*)&sx[nxt][o] = hx;
                *(ushort4*)&sw[nxt][o] = hw;
            }
            cur = nxt;
        }
    }

    // epilogue (layout verified R18/R20-R23): D col=lane&15, row=(lane>>4)*4+j
#pragma unroll
    for (int fn = 0; fn < 4; ++fn) {
        int col = n0 + wc * 64 + fn * 16 + (lane & 15);
        float bc = g0 * bias[e0 * ND + col] + g1 * bias[e1 * ND + col];
#pragma unroll
        for (int fm = 0; fm < 4; ++fm) {
            int rbase = wr * 64 + fm * 16 + (lane >> 4) * 4;
#pragma unroll
            for (int j = 0; j < 4; ++j)
                out32[((size_t)b * NL + rbase + j) * ND + col] = enc_bf16_hi(acc[fm][fn][j] + bc);
        }
    }
}

// ---------------- fallback (R20 kernel, verified) for small ws ----------------
__global__ __launch_bounds__(256)
void moe_mfma_fb_kernel(const float* __restrict__ x, const float* __restrict__ W,
                        const float* __restrict__ bias, const int* __restrict__ eidx,
                        const float* __restrict__ gval, unsigned int* __restrict__ out32) {
    __shared__ unsigned short xh[128 * 40], xl[128 * 40];
    __shared__ unsigned short wh[128 * 40], wl[128 * 40];
    const int b = blockIdx.y, n0 = blockIdx.x * 128;
    const int t = threadIdx.x, lane = t & 63, wid = t >> 6;
    const int wr = wid >> 1, wc = wid & 1;
    const int e0 = eidx[2 * b], e1 = eidx[2 * b + 1];
    const float g0 = gval[2 * b], g1 = gval[2 * b + 1];
    const float* xb = x + (size_t)b * NL * NF;
    const float* W0 = W + (size_t)e0 * NF * ND + n0;
    const float* W1 = W + (size_t)e1 * NF * ND + n0;
    f32x4 acc[4][4] = {};
    for (int k0 = 0; k0 < 928; k0 += 32) {
#pragma unroll
        for (int p = 0; p < 4; ++p) {
            int idx = t + 256 * p, row = idx >> 3, c4 = idx & 7, f = k0 + 4 * c4;
            float4 v; v.x = v.y = v.z = v.w = 0.f;
            if (f + 3 < NF) v = *(const float4*)(xb + (size_t)row * NF + f);
            ushort4 h, lo;
            split2(v.x, h.x, lo.x); split2(v.y, h.y, lo.y);
            split2(v.z, h.z, lo.z); split2(v.w, h.w, lo.w);
            *(ushort4*)&xh[row * 40 + 4 * c4] = h; *(ushort4*)&xl[row * 40 + 4 * c4] = lo;
        }
#pragma unroll
        for (int p = 0; p < 8; ++p) {
            int idx = t + 256 * p, c = idx & 127, kp = idx >> 7, f = k0 + 2 * kp;
            float u0 = 0.f, u1 = 0.f;
            if (f < NF)     u0 = g0 * W0[(size_t)f * ND + c] + g1 * W1[(size_t)f * ND + c];
            if (f + 1 < NF) u1 = g0 * W0[(size_t)(f + 1) * ND + c] + g1 * W1[(size_t)(f + 1) * ND + c];
            unsigned short h0, l0, h1, l1;
            split2(u0, h0, l0); split2(u1, h1, l1);
            *(unsigned int*)&wh[c * 40 + 2 * kp] = (unsigned int)h0 | ((unsigned int)h1 << 16);
            *(unsigned int*)&wl[c * 40 + 2 * kp] = (unsigned int)l0 | ((unsigned int)l1 << 16);
        }
        __syncthreads();
        bf16x8 ah[4], al[4], bh[4], bl[4];
#pragma unroll
        for (int fm = 0; fm < 4; ++fm) {
            int off = (wr * 64 + fm * 16 + (lane & 15)) * 40 + (lane >> 4) * 8;
            ah[fm] = read8b(&xh[off]); al[fm] = read8b(&xl[off]);
        }
#pragma unroll
        for (int fn = 0; fn < 4; ++fn) {
            int off = (wc * 64 + fn * 16 + (lane & 15)) * 40 + (lane >> 4) * 8;
            bh[fn] = read8b(&wh[off]); bl[fn] = read8b(&wl[off]);
        }
#pragma unroll
        for (int fm = 0; fm < 4; ++fm)
#pragma unroll
            for (int fn = 0; fn < 4; ++fn) {
                acc[fm][fn] = __builtin_amdgcn_mfma_f32_16x16x32_bf16(ah[fm], bh[fn], acc[fm][fn], 0, 0, 0);
                acc[fm][fn] = __builtin_amdgcn_mfma_f32_16x16x32_bf16(ah[fm], bl[fn], acc[fm][fn], 0, 0, 0);
                acc[fm][fn] = __builtin_amdgcn_mfma_f32_16x16x32_bf16(al[fm], bh[fn], acc[fm][fn], 0, 0, 0);
            }
        __syncthreads();
    }
#pragma unroll
    for (int fn = 0; fn < 4; ++fn) {
        int col = n0 + wc * 64 + fn * 16 + (lane & 15);
        float bc = g0 * bias[e0 * ND + col] + g1 * bias[e1 * ND + col];
#pragma unroll
        for (int fm = 0; fm < 4; ++fm) {
            int rbase = wr * 64 + fm * 16 + (lane >> 4) * 4;
#pragma unroll
            for (int j = 0; j < 4; ++j)
                out32[((size_t)b * NL + rbase + j) * ND + col] = enc_bf16_hi(acc[fm][fn][j] + bc);
        }
    }
}

extern "C" void kernel_launch(void* const* d_in, const int* in_sizes, int n_in,
                              void* d_out, int out_size, void* d_ws, size_t ws_size,
                              hipStream_t stream) {
    const float* x      = (const float*)d_in[0];
    const float* logits = (const float*)d_in[1];
    const int*   masks  = (const int*)d_in[2];
    const float* W      = (const float*)d_in[3];
    const float* bias   = (const float*)d_in[4];
    unsigned int* out32 = (unsigned int*)d_out;

    int*   eidx = (int*)d_ws;
    float* gval = (float*)((char*)d_ws + 4096);

    gates_kernel<<<dim3(2), dim3(256), 0, stream>>>(logits, masks, eidx, gval);

    if (ws_size >= WT_OFF + WT_BYTES) {
        float* Wt = (float*)((char*)d_ws + WT_OFF);
        wt_kernel<<<dim3(29, 16, 8), dim3(256), 0, stream>>>(W, Wt);
        moe_mfma_h_kernel<<<dim3(ND / 128, NB), dim3(256), 0, stream>>>(
            x, Wt, bias, eidx, gval, out32);
    } else {
        moe_mfma_fb_kernel<<<dim3(ND / 128, NB), dim3(256), 0, stream>>>(
            x, W, bias, eidx, gval, out32);
    }
}

// Round 25
// 329.286 us; speedup vs baseline: 4.0816x; 1.5413x over previous
//
#include <hip/hip_runtime.h>
#include <hip/hip_bf16.h>

#define NB 512
#define NL 128
#define NF 900
#define ND 512
#define NE 8
#define FP 928                       // padded K (29 * 32), zero-filled
#define LSTR 36                      // LDS row stride (ushorts)
#define X16_OFF 8192
#define X16_BYTES ((size_t)NB * NL * FP * 2)
#define WT16_OFF (X16_OFF + X16_BYTES)
#define WT16_BYTES ((size_t)NE * ND * FP * 2)

typedef _Float16 f16x8 __attribute__((ext_vector_type(8)));
typedef short bf16x8 __attribute__((ext_vector_type(8)));
typedef float f32x4 __attribute__((ext_vector_type(4)));

// Output encoding (measured R5-R18; R18/R20-R24 PASSED): u32 slots, bf16 in HIGH u16.
static __device__ __forceinline__ unsigned int enc_bf16_hi(float v) {
    unsigned int u = __float_as_uint(v);
    return (u + 0x7FFFu + ((u >> 16) & 1u)) & 0xFFFF0000u;
}
static __device__ __forceinline__ unsigned short bf16r(float v) {
    unsigned int u = __float_as_uint(v);
    return (unsigned short)((u + 0x7FFFu + ((u >> 16) & 1u)) >> 16);
}
static __device__ __forceinline__ float b2f(unsigned short h) {
    return __uint_as_float(((unsigned int)h) << 16);
}
static __device__ __forceinline__ void split2(float v, unsigned short& hi, unsigned short& lo) {
    hi = bf16r(v); lo = bf16r(v - b2f(hi));
}
static __device__ __forceinline__ unsigned short f16b(float v) {
    _Float16 h = (_Float16)v;
    return __builtin_bit_cast(unsigned short, h);
}
static __device__ __forceinline__ unsigned int pk16(float a, float b) {
    return (unsigned int)f16b(a) | ((unsigned int)f16b(b) << 16);
}
static __device__ __forceinline__ f16x8 read8h(const unsigned short* p) {
    union { ushort4 u[2]; f16x8 v; } r;
    r.u[0] = *(const ushort4*)(p);
    r.u[1] = *(const ushort4*)(p + 4);
    return r.v;
}
static __device__ __forceinline__ bf16x8 read8b(const unsigned short* p) {
    union { ushort4 u[2]; bf16x8 v; } r;
    r.u[0] = *(const ushort4*)(p);
    r.u[1] = *(const ushort4*)(p + 4);
    return r.v;
}

// ---------------- H0 gates (verified) ----------------
__global__ void gates_kernel(const float* __restrict__ logits,
                             const int* __restrict__ masks,
                             int* __restrict__ eidx,
                             float* __restrict__ gval) {
    int b = blockIdx.x * blockDim.x + threadIdx.x;
    if (b >= NB) return;
    float l[NE], pr[NE], pm[NE];
    int mk[NE];
    float mx = -3.0e38f;
    for (int e = 0; e < NE; ++e) {
        l[e] = logits[b * NE + e];
        mk[e] = masks[b * NE + e];
        mx = fmaxf(mx, l[e]);
    }
    float Z = 0.f;
    for (int e = 0; e < NE; ++e) { pr[e] = expf(l[e] - mx); Z += pr[e]; }
    for (int e = 0; e < NE; ++e) { pr[e] /= Z; pm[e] = (mk[e] == 1) ? pr[e] : 0.f; }
    int i1 = 0;
    for (int e = 1; e < NE; ++e) if (pm[e] > pm[i1]) i1 = e;
    int i2 = (i1 == 0) ? 1 : 0;
    for (int e = 0; e < NE; ++e) if (e != i1 && pm[e] > pm[i2]) i2 = e;
    float v1 = pm[i1], v2 = pm[i2];
    float den = v1 + v2 + 1e-9f;
    eidx[2 * b] = i1; eidx[2 * b + 1] = i2;
    gval[2 * b] = v1 / den; gval[2 * b + 1] = v2 / den;
}

// ---------------- x -> fp16, padded rows of FP ----------------
__global__ void cvt_x_kernel(const float* __restrict__ x, unsigned int* __restrict__ x16) {
    const int NJ = FP / 8;                       // 116 8-elem chunks per row
    const long total = (long)NB * NL * NJ;
    for (long i = (long)blockIdx.x * blockDim.x + threadIdx.x; i < total;
         i += (long)gridDim.x * blockDim.x) {
        long row = i / NJ;
        int  j   = (int)(i % NJ);
        int  f   = 8 * j;
        const float* src = x + row * NF + f;
        float v[8];
#pragma unroll
        for (int e = 0; e < 8; ++e) v[e] = (f + e < NF) ? src[e] : 0.f;
        uint4 pk;
        pk.x = pk16(v[0], v[1]); pk.y = pk16(v[2], v[3]);
        pk.z = pk16(v[4], v[5]); pk.w = pk16(v[6], v[7]);
        *(uint4*)(x16 + (row * FP + f) / 2) = pk;
    }
}

// ---------------- W -> transposed fp16: Wt16[e][d][f], padded ----------------
__global__ void wt16_kernel(const float* __restrict__ W, unsigned int* __restrict__ Wt16) {
    __shared__ float tile[32][33];
    const int e = blockIdx.z, f0 = blockIdx.x * 32, d0 = blockIdx.y * 32;
    const int tx = threadIdx.x & 31, ty = threadIdx.x >> 5;   // 32 x 8
    const float* Wb = W + (size_t)e * NF * ND;
#pragma unroll
    for (int i = 0; i < 4; ++i) {
        int f = f0 + ty + 8 * i;
        tile[ty + 8 * i][tx] = (f < NF) ? Wb[(size_t)f * ND + d0 + tx] : 0.f;
    }
    __syncthreads();
    const int tx2 = threadIdx.x & 15, ty2 = threadIdx.x >> 4;  // 16 x 16
#pragma unroll
    for (int i = 0; i < 2; ++i) {
        int d = d0 + ty2 + 16 * i;
        int f = f0 + 2 * tx2;
        unsigned int pk = pk16(tile[2 * tx2][ty2 + 16 * i], tile[2 * tx2 + 1][ty2 + 16 * i]);
        Wt16[((size_t)e * ND + d) * FP / 2 + f / 2] = pk;
    }
}

// ---------------- fp16 MFMA GEMM: depth-3 reg pipeline, dbuf, 1 barrier/step ----------------
struct RegSet { uint4 xa, xb_, w0a, w0b, w1a, w1b; };

__global__ __launch_bounds__(256, 3)
void moe_mfma_h3_kernel(const unsigned short* __restrict__ x16,
                        const unsigned short* __restrict__ Wt16,
                        const float* __restrict__ bias,
                        const int* __restrict__ eidx,
                        const float* __restrict__ gval,
                        unsigned int* __restrict__ out32) {
    __shared__ unsigned short sx[2][128 * LSTR];
    __shared__ unsigned short sw[2][128 * LSTR];

    const int b = blockIdx.y, n0 = blockIdx.x * 128;
    const int t = threadIdx.x, lane = t & 63, wid = t >> 6;
    const int wr = wid >> 1, wc = wid & 1;

    const int e0 = eidx[2 * b], e1 = eidx[2 * b + 1];
    const float g0 = gval[2 * b], g1 = gval[2 * b + 1];
    const _Float16 g0h = (_Float16)g0, g1h = (_Float16)g1;
    f16x8 g08, g18;
#pragma unroll
    for (int i = 0; i < 8; ++i) { g08[i] = g0h; g18[i] = g1h; }

    const unsigned short* xb = x16 + (size_t)b * NL * FP;
    const unsigned short* T0 = Wt16 + ((size_t)e0 * ND + n0) * FP;
    const unsigned short* T1 = Wt16 + ((size_t)e1 * ND + n0) * FP;

    const int row = t >> 1;          // 0..127
    const int hf  = t & 1;           // which 16-elem half of the 32-k tile

    f32x4 acc[4][4] = {};
    RegSet Ra, Rb;

#define LOAD_SET(R, tile_)                                                   \
    {                                                                        \
        int f_ = (tile_) * 32 + 16 * hf;                                     \
        (R).xa  = *(const uint4*)(xb + (size_t)row * FP + f_);               \
        (R).xb_ = *(const uint4*)(xb + (size_t)row * FP + f_ + 8);           \
        (R).w0a = *(const uint4*)(T0 + (size_t)row * FP + f_);               \
        (R).w0b = *(const uint4*)(T0 + (size_t)row * FP + f_ + 8);           \
        (R).w1a = *(const uint4*)(T1 + (size_t)row * FP + f_);               \
        (R).w1b = *(const uint4*)(T1 + (size_t)row * FP + f_ + 8);           \
    }

#define WRITE_SET(R, buf_)                                                   \
    {                                                                        \
        int o_ = row * LSTR + 16 * hf;                                       \
        *(uint2*)&sx[buf_][o_]     = make_uint2((R).xa.x, (R).xa.y);         \
        *(uint2*)&sx[buf_][o_ + 4] = make_uint2((R).xa.z, (R).xa.w);         \
        *(uint2*)&sx[buf_][o_ + 8] = make_uint2((R).xb_.x, (R).xb_.y);       \
        *(uint2*)&sx[buf_][o_ +12] = make_uint2((R).xb_.z, (R).xb_.w);       \
        f16x8 w0A = __builtin_bit_cast(f16x8, (R).w0a);                      \
        f16x8 w0B = __builtin_bit_cast(f16x8, (R).w0b);                      \
        f16x8 w1A = __builtin_bit_cast(f16x8, (R).w1a);                      \
        f16x8 w1B = __builtin_bit_cast(f16x8, (R).w1b);                      \
        f16x8 bA = w0A * g08 + w1A * g18;                                    \
        f16x8 bB = w0B * g08 + w1B * g18;                                    \
        uint4 uA = __builtin_bit_cast(uint4, bA);                            \
        uint4 uB = __builtin_bit_cast(uint4, bB);                            \
        *(uint2*)&sw[buf_][o_]     = make_uint2(uA.x, uA.y);                 \
        *(uint2*)&sw[buf_][o_ + 4] = make_uint2(uA.z, uA.w);                 \
        *(uint2*)&sw[buf_][o_ + 8] = make_uint2(uB.x, uB.y);                 \
        *(uint2*)&sw[buf_][o_ +12] = make_uint2(uB.z, uB.w);                 \
    }

    // prologue: tile0 -> LDS[0]; tile1 -> Ra; tile2 -> Rb
    LOAD_SET(Ra, 0)
    WRITE_SET(Ra, 0)
    LOAD_SET(Ra, 1)
    LOAD_SET(Rb, 2)

    int cur = 0;
    for (int s = 0; s < 29; ++s) {
        __syncthreads();             // LDS[cur] = tile s complete; prev reads done
        if (s & 1) {
            if (s < 28) WRITE_SET(Rb, cur ^ 1)      // tile s+1
            if (s < 26) LOAD_SET(Rb, s + 3)
        } else {
            if (s < 28) WRITE_SET(Ra, cur ^ 1)
            if (s < 26) LOAD_SET(Ra, s + 3)
        }
        f16x8 af[4], bf[4];
#pragma unroll
        for (int fm = 0; fm < 4; ++fm) {
            int o = (wr * 64 + fm * 16 + (lane & 15)) * LSTR + (lane >> 4) * 8;
            af[fm] = read8h(&sx[cur][o]);
        }
#pragma unroll
        for (int fn = 0; fn < 4; ++fn) {
            int o = (wc * 64 + fn * 16 + (lane & 15)) * LSTR + (lane >> 4) * 8;
            bf[fn] = read8h(&sw[cur][o]);
        }
#pragma unroll
        for (int fm = 0; fm < 4; ++fm)
#pragma unroll
            for (int fn = 0; fn < 4; ++fn)
                acc[fm][fn] = __builtin_amdgcn_mfma_f32_16x16x32_f16(
                    af[fm], bf[fn], acc[fm][fn], 0, 0, 0);
        cur ^= 1;
    }

    // epilogue (layout verified): D col=lane&15, row=(lane>>4)*4+j
#pragma unroll
    for (int fn = 0; fn < 4; ++fn) {
        int col = n0 + wc * 64 + fn * 16 + (lane & 15);
        float bc = g0 * bias[e0 * ND + col] + g1 * bias[e1 * ND + col];
#pragma unroll
        for (int fm = 0; fm < 4; ++fm) {
            int rbase = wr * 64 + fm * 16 + (lane >> 4) * 4;
#pragma unroll
            for (int j = 0; j < 4; ++j)
                out32[((size_t)b * NL + rbase + j) * ND + col] = enc_bf16_hi(acc[fm][fn][j] + bc);
        }
    }
#undef LOAD_SET
#undef WRITE_SET
}

// ---------------- fallback (R20 kernel, verified 1612us) for small ws ----------------
__global__ __launch_bounds__(256)
void moe_mfma_fb_kernel(const float* __restrict__ x, const float* __restrict__ W,
                        const float* __restrict__ bias, const int* __restrict__ eidx,
                        const float* __restrict__ gval, unsigned int* __restrict__ out32) {
    __shared__ unsigned short xh[128 * 40], xl[128 * 40];
    __shared__ unsigned short wh[128 * 40], wl[128 * 40];
    const int b = blockIdx.y, n0 = blockIdx.x * 128;
    const int t = threadIdx.x, lane = t & 63, wid = t >> 6;
    const int wr = wid >> 1, wc = wid & 1;
    const int e0 = eidx[2 * b], e1 = eidx[2 * b + 1];
    const float g0 = gval[2 * b], g1 = gval[2 * b + 1];
    const float* xb = x + (size_t)b * NL * NF;
    const float* W0 = W + (size_t)e0 * NF * ND + n0;
    const float* W1 = W + (size_t)e1 * NF * ND + n0;
    f32x4 acc[4][4] = {};
    for (int k0 = 0; k0 < 928; k0 += 32) {
#pragma unroll
        for (int p = 0; p < 4; ++p) {
            int idx = t + 256 * p, row = idx >> 3, c4 = idx & 7, f = k0 + 4 * c4;
            float4 v; v.x = v.y = v.z = v.w = 0.f;
            if (f + 3 < NF) v = *(const float4*)(xb + (size_t)row * NF + f);
            ushort4 h, lo;
            split2(v.x, h.x, lo.x); split2(v.y, h.y, lo.y);
            split2(v.z, h.z, lo.z); split2(v.w, h.w, lo.w);
            *(ushort4*)&xh[row * 40 + 4 * c4] = h; *(ushort4*)&xl[row * 40 + 4 * c4] = lo;
        }
#pragma unroll
        for (int p = 0; p < 8; ++p) {
            int idx = t + 256 * p, c = idx & 127, kp = idx >> 7, f = k0 + 2 * kp;
            float u0 = 0.f, u1 = 0.f;
            if (f < NF)     u0 = g0 * W0[(size_t)f * ND + c] + g1 * W1[(size_t)f * ND + c];
            if (f + 1 < NF) u1 = g0 * W0[(size_t)(f + 1) * ND + c] + g1 * W1[(size_t)(f + 1) * ND + c];
            unsigned short h0, l0, h1, l1;
            split2(u0, h0, l0); split2(u1, h1, l1);
            *(unsigned int*)&wh[c * 40 + 2 * kp] = (unsigned int)h0 | ((unsigned int)h1 << 16);
            *(unsigned int*)&wl[c * 40 + 2 * kp] = (unsigned int)l0 | ((unsigned int)l1 << 16);
        }
        __syncthreads();
        bf16x8 ah[4], al[4], bh[4], bl[4];
#pragma unroll
        for (int fm = 0; fm < 4; ++fm) {
            int off = (wr * 64 + fm * 16 + (lane & 15)) * 40 + (lane >> 4) * 8;
            ah[fm] = read8b(&xh[off]); al[fm] = read8b(&xl[off]);
        }
#pragma unroll
        for (int fn = 0; fn < 4; ++fn) {
            int off = (wc * 64 + fn * 16 + (lane & 15)) * 40 + (lane >> 4) * 8;
            bh[fn] = read8b(&wh[off]); bl[fn] = read8b(&wl[off]);
        }
#pragma unroll
        for (int fm = 0; fm < 4; ++fm)
#pragma unroll
            for (int fn = 0; fn < 4; ++fn) {
                acc[fm][fn] = __builtin_amdgcn_mfma_f32_16x16x32_bf16(ah[fm], bh[fn], acc[fm][fn], 0, 0, 0);
                acc[fm][fn] = __builtin_amdgcn_mfma_f32_16x16x32_bf16(ah[fm], bl[fn], acc[fm][fn], 0, 0, 0);
                acc[fm][fn] = __builtin_amdgcn_mfma_f32_16x16x32_bf16(al[fm], bh[fn], acc[fm][fn], 0, 0, 0);
            }
        __syncthreads();
    }
#pragma unroll
    for (int fn = 0; fn < 4; ++fn) {
        int col = n0 + wc * 64 + fn * 16 + (lane & 15);
        float bc = g0 * bias[e0 * ND + col] + g1 * bias[e1 * ND + col];
#pragma unroll
        for (int fm = 0; fm < 4; ++fm) {
            int rbase = wr * 64 + fm * 16 + (lane >> 4) * 4;
#pragma unroll
            for (int j = 0; j < 4; ++j)
                out32[((size_t)b * NL + rbase + j) * ND + col] = enc_bf16_hi(acc[fm][fn][j] + bc);
        }
    }
}

extern "C" void kernel_launch(void* const* d_in, const int* in_sizes, int n_in,
                              void* d_out, int out_size, void* d_ws, size_t ws_size,
                              hipStream_t stream) {
    const float* x      = (const float*)d_in[0];
    const float* logits = (const float*)d_in[1];
    const int*   masks  = (const int*)d_in[2];
    const float* W      = (const float*)d_in[3];
    const float* bias   = (const float*)d_in[4];
    unsigned int* out32 = (unsigned int*)d_out;

    int*   eidx = (int*)d_ws;
    float* gval = (float*)((char*)d_ws + 4096);

    gates_kernel<<<dim3(2), dim3(256), 0, stream>>>(logits, masks, eidx, gval);

    if (ws_size >= WT16_OFF + WT16_BYTES) {
        unsigned int* x16u  = (unsigned int*)((char*)d_ws + X16_OFF);
        unsigned int* wt16u = (unsigned int*)((char*)d_ws + WT16_OFF);
        cvt_x_kernel<<<dim3(4096), dim3(256), 0, stream>>>(x, x16u);
        wt16_kernel<<<dim3(FP / 32, ND / 32, NE), dim3(256), 0, stream>>>(W, wt16u);
        moe_mfma_h3_kernel<<<dim3(ND / 128, NB), dim3(256), 0, stream>>>(
            (const unsigned short*)x16u, (const unsigned short*)wt16u,
            bias, eidx, gval, out32);
    } else {
        moe_mfma_fb_kernel<<<dim3(ND / 128, NB), dim3(256), 0, stream>>>(
            x, W, bias, eidx, gval, out32);
    }
}

// Round 26
// 322.885 us; speedup vs baseline: 4.1625x; 1.0198x over previous
//
#include <hip/hip_runtime.h>
#include <hip/hip_bf16.h>

#define NB 512
#define NL 128
#define NF 900
#define ND 512
#define NE 8
#define FP 928                       // padded K for W (29 * 32)
#define LSTR 40                      // LDS row stride (ushorts): 80B rows, 16B-aligned frags
#define WT16_OFF 8192
#define WT16_BYTES ((size_t)NE * ND * FP * 2)

typedef _Float16 f16x8 __attribute__((ext_vector_type(8)));
typedef short bf16x8 __attribute__((ext_vector_type(8)));
typedef float f32x4 __attribute__((ext_vector_type(4)));

// Output encoding (measured R5-R18; R18/R20-R25 PASSED): u32 slots, bf16 in HIGH u16.
static __device__ __forceinline__ unsigned int enc_bf16_hi(float v) {
    unsigned int u = __float_as_uint(v);
    return (u + 0x7FFFu + ((u >> 16) & 1u)) & 0xFFFF0000u;
}
static __device__ __forceinline__ unsigned short bf16r(float v) {
    unsigned int u = __float_as_uint(v);
    return (unsigned short)((u + 0x7FFFu + ((u >> 16) & 1u)) >> 16);
}
static __device__ __forceinline__ float b2f(unsigned short h) {
    return __uint_as_float(((unsigned int)h) << 16);
}
static __device__ __forceinline__ void split2(float v, unsigned short& hi, unsigned short& lo) {
    hi = bf16r(v); lo = bf16r(v - b2f(hi));
}
static __device__ __forceinline__ unsigned short f16b(float v) {
    _Float16 h = (_Float16)v;                      // v_cvt_f16_f32 (RNE)
    return __builtin_bit_cast(unsigned short, h);
}
static __device__ __forceinline__ unsigned int pk16(float a, float b) {
    return (unsigned int)f16b(a) | ((unsigned int)f16b(b) << 16);
}
static __device__ __forceinline__ bf16x8 read8b(const unsigned short* p) {
    union { ushort4 u[2]; bf16x8 v; } r;
    r.u[0] = *(const ushort4*)(p);
    r.u[1] = *(const ushort4*)(p + 4);
    return r.v;
}

// ---------------- H0 gates (verified) ----------------
__global__ void gates_kernel(const float* __restrict__ logits,
                             const int* __restrict__ masks,
                             int* __restrict__ eidx,
                             float* __restrict__ gval) {
    int b = blockIdx.x * blockDim.x + threadIdx.x;
    if (b >= NB) return;
    float l[NE], pr[NE], pm[NE];
    int mk[NE];
    float mx = -3.0e38f;
    for (int e = 0; e < NE; ++e) {
        l[e] = logits[b * NE + e];
        mk[e] = masks[b * NE + e];
        mx = fmaxf(mx, l[e]);
    }
    float Z = 0.f;
    for (int e = 0; e < NE; ++e) { pr[e] = expf(l[e] - mx); Z += pr[e]; }
    for (int e = 0; e < NE; ++e) { pr[e] /= Z; pm[e] = (mk[e] == 1) ? pr[e] : 0.f; }
    int i1 = 0;
    for (int e = 1; e < NE; ++e) if (pm[e] > pm[i1]) i1 = e;
    int i2 = (i1 == 0) ? 1 : 0;
    for (int e = 0; e < NE; ++e) if (e != i1 && pm[e] > pm[i2]) i2 = e;
    float v1 = pm[i1], v2 = pm[i2];
    float den = v1 + v2 + 1e-9f;
    eidx[2 * b] = i1; eidx[2 * b + 1] = i2;
    gval[2 * b] = v1 / den; gval[2 * b + 1] = v2 / den;
}

// ---------------- W -> transposed fp16: Wt16[e][d][f], zero-padded to FP ----------------
__global__ void wt16_kernel(const float* __restrict__ W, unsigned int* __restrict__ Wt16) {
    __shared__ float tile[32][33];
    const int e = blockIdx.z, f0 = blockIdx.x * 32, d0 = blockIdx.y * 32;
    const int tx = threadIdx.x & 31, ty = threadIdx.x >> 5;   // 32 x 8
    const float* Wb = W + (size_t)e * NF * ND;
#pragma unroll
    for (int i = 0; i < 4; ++i) {
        int f = f0 + ty + 8 * i;
        tile[ty + 8 * i][tx] = (f < NF) ? Wb[(size_t)f * ND + d0 + tx] : 0.f;
    }
    __syncthreads();
    const int tx2 = threadIdx.x & 15, ty2 = threadIdx.x >> 4;  // 16 x 16
#pragma unroll
    for (int i = 0; i < 2; ++i) {
        int d = d0 + ty2 + 16 * i;
        int f = f0 + 2 * tx2;
        unsigned int pk = pk16(tile[2 * tx2][ty2 + 16 * i], tile[2 * tx2 + 1][ty2 + 16 * i]);
        Wt16[((size_t)e * ND + d) * FP / 2 + f / 2] = pk;
    }
}

// ---------------- fused-cvt fp16 MFMA GEMM: depth-3 pipeline, dbuf, 1 barrier/step ----------------
struct RegSet { float4 x0, x1, x2, x3; uint4 w0a, w0b, w1a, w1b; };

static __device__ __forceinline__ float4 gf4(const float* p, int f, int lim) {
    float4 v;
    v.x = (f     < lim) ? p[0] : 0.f;
    v.y = (f + 1 < lim) ? p[1] : 0.f;
    v.z = (f + 2 < lim) ? p[2] : 0.f;
    v.w = (f + 3 < lim) ? p[3] : 0.f;
    return v;
}

__global__ __launch_bounds__(256, 3)
void moe_mfma_h4_kernel(const float* __restrict__ x,
                        const unsigned short* __restrict__ Wt16,
                        const float* __restrict__ bias,
                        const int* __restrict__ eidx,
                        const float* __restrict__ gval,
                        unsigned int* __restrict__ out32) {
    __shared__ unsigned short sx[2][128 * LSTR];
    __shared__ unsigned short sw[2][128 * LSTR];

    const int b = blockIdx.y, n0 = blockIdx.x * 128;
    const int t = threadIdx.x, lane = t & 63, wid = t >> 6;
    const int wr = wid >> 1, wc = wid & 1;

    const int e0 = eidx[2 * b], e1 = eidx[2 * b + 1];
    const float g0 = gval[2 * b], g1 = gval[2 * b + 1];
    const _Float16 g0h = (_Float16)g0, g1h = (_Float16)g1;
    f16x8 g08, g18;
#pragma unroll
    for (int i = 0; i < 8; ++i) { g08[i] = g0h; g18[i] = g1h; }

    const float* xb = x + (size_t)b * NL * NF;
    const unsigned short* T0 = Wt16 + ((size_t)e0 * ND + n0) * FP;
    const unsigned short* T1 = Wt16 + ((size_t)e1 * ND + n0) * FP;

    const int row = t >> 1;          // 0..127 (x row / W col)
    const int hf  = t & 1;           // 16-k half of the 32-k tile

    f32x4 acc[4][4] = {};
    RegSet Ra, Rb;

#define LOAD_SET(R, tile_)                                                    \
    {                                                                         \
        int f_ = (tile_) * 32 + 16 * hf;                                      \
        const float* xs_ = xb + (size_t)row * NF + f_;                        \
        if (f_ + 16 <= NF) {                                                  \
            (R).x0 = *(const float4*)(xs_);                                   \
            (R).x1 = *(const float4*)(xs_ + 4);                               \
            (R).x2 = *(const float4*)(xs_ + 8);                               \
            (R).x3 = *(const float4*)(xs_ + 12);                              \
        } else {   /* tail tile 28: guarded, zero-fill (W pad is 0) */        \
            (R).x0 = gf4(xs_,      f_,      NF);                              \
            (R).x1 = gf4(xs_ + 4,  f_ + 4,  NF);                              \
            (R).x2 = gf4(xs_ + 8,  f_ + 8,  NF);                              \
            (R).x3 = gf4(xs_ + 12, f_ + 12, NF);                              \
        }                                                                     \
        (R).w0a = *(const uint4*)(T0 + (size_t)row * FP + f_);                \
        (R).w0b = *(const uint4*)(T0 + (size_t)row * FP + f_ + 8);            \
        (R).w1a = *(const uint4*)(T1 + (size_t)row * FP + f_);                \
        (R).w1b = *(const uint4*)(T1 + (size_t)row * FP + f_ + 8);            \
    }

#define WRITE_SET(R, buf_)                                                    \
    {                                                                         \
        int o_ = row * LSTR + 16 * hf;                                        \
        uint4 hx0, hx1;                                                       \
        hx0.x = pk16((R).x0.x, (R).x0.y); hx0.y = pk16((R).x0.z, (R).x0.w);   \
        hx0.z = pk16((R).x1.x, (R).x1.y); hx0.w = pk16((R).x1.z, (R).x1.w);   \
        hx1.x = pk16((R).x2.x, (R).x2.y); hx1.y = pk16((R).x2.z, (R).x2.w);   \
        hx1.z = pk16((R).x3.x, (R).x3.y); hx1.w = pk16((R).x3.z, (R).x3.w);   \
        *(uint4*)&sx[buf_][o_]     = hx0;                                     \
        *(uint4*)&sx[buf_][o_ + 8] = hx1;                                     \
        f16x8 w0A = __builtin_bit_cast(f16x8, (R).w0a);                       \
        f16x8 w0B = __builtin_bit_cast(f16x8, (R).w0b);                       \
        f16x8 w1A = __builtin_bit_cast(f16x8, (R).w1a);                       \
        f16x8 w1B = __builtin_bit_cast(f16x8, (R).w1b);                       \
        f16x8 bA = w0A * g08 + w1A * g18;                                     \
        f16x8 bB = w0B * g08 + w1B * g18;                                     \
        *(uint4*)&sw[buf_][o_]     = __builtin_bit_cast(uint4, bA);           \
        *(uint4*)&sw[buf_][o_ + 8] = __builtin_bit_cast(uint4, bB);           \
    }

    // prologue: tile0 -> LDS[0] via Ra; tile1 -> Ra; tile2 -> Rb
    LOAD_SET(Ra, 0)
    WRITE_SET(Ra, 0)
    LOAD_SET(Ra, 1)
    LOAD_SET(Rb, 2)

    int cur = 0;
    for (int s = 0; s < 29; ++s) {
        __syncthreads();             // LDS[cur] = tile s ready; prior reads drained
        if (s & 1) {
            if (s < 28) WRITE_SET(Rb, cur ^ 1)
            if (s < 26) LOAD_SET(Rb, s + 3)
        } else {
            if (s < 28) WRITE_SET(Ra, cur ^ 1)
            if (s < 26) LOAD_SET(Ra, s + 3)
        }
        f16x8 af[4], bf[4];
#pragma unroll
        for (int fm = 0; fm < 4; ++fm) {
            int o = (wr * 64 + fm * 16 + (lane & 15)) * LSTR + (lane >> 4) * 8;
            af[fm] = *(const f16x8*)&sx[cur][o];      // single ds_read_b128 (16B-aligned)
        }
#pragma unroll
        for (int fn = 0; fn < 4; ++fn) {
            int o = (wc * 64 + fn * 16 + (lane & 15)) * LSTR + (lane >> 4) * 8;
            bf[fn] = *(const f16x8*)&sw[cur][o];
        }
#pragma unroll
        for (int fm = 0; fm < 4; ++fm)
#pragma unroll
            for (int fn = 0; fn < 4; ++fn)
                acc[fm][fn] = __builtin_amdgcn_mfma_f32_16x16x32_f16(
                    af[fm], bf[fn], acc[fm][fn], 0, 0, 0);
        cur ^= 1;
    }

    // epilogue (layout verified): D col=lane&15, row=(lane>>4)*4+j
#pragma unroll
    for (int fn = 0; fn < 4; ++fn) {
        int col = n0 + wc * 64 + fn * 16 + (lane & 15);
        float bc = g0 * bias[e0 * ND + col] + g1 * bias[e1 * ND + col];
#pragma unroll
        for (int fm = 0; fm < 4; ++fm) {
            int rbase = wr * 64 + fm * 16 + (lane >> 4) * 4;
#pragma unroll
            for (int j = 0; j < 4; ++j)
                out32[((size_t)b * NL + rbase + j) * ND + col] = enc_bf16_hi(acc[fm][fn][j] + bc);
        }
    }
#undef LOAD_SET
#undef WRITE_SET
}

// ---------------- fallback (R20 kernel, verified) for small ws ----------------
__global__ __launch_bounds__(256)
void moe_mfma_fb_kernel(const float* __restrict__ x, const float* __restrict__ W,
                        const float* __restrict__ bias, const int* __restrict__ eidx,
                        const float* __restrict__ gval, unsigned int* __restrict__ out32) {
    __shared__ unsigned short xh[128 * 40], xl[128 * 40];
    __shared__ unsigned short wh[128 * 40], wl[128 * 40];
    const int b = blockIdx.y, n0 = blockIdx.x * 128;
    const int t = threadIdx.x, lane = t & 63, wid = t >> 6;
    const int wr = wid >> 1, wc = wid & 1;
    const int e0 = eidx[2 * b], e1 = eidx[2 * b + 1];
    const float g0 = gval[2 * b], g1 = gval[2 * b + 1];
    const float* xb = x + (size_t)b * NL * NF;
    const float* W0 = W + (size_t)e0 * NF * ND + n0;
    const float* W1 = W + (size_t)e1 * NF * ND + n0;
    f32x4 acc[4][4] = {};
    for (int k0 = 0; k0 < 928; k0 += 32) {
#pragma unroll
        for (int p = 0; p < 4; ++p) {
            int idx = t + 256 * p, row = idx >> 3, c4 = idx & 7, f = k0 + 4 * c4;
            float4 v; v.x = v.y = v.z = v.w = 0.f;
            if (f + 3 < NF) v = *(const float4*)(xb + (size_t)row * NF + f);
            ushort4 h, lo;
            split2(v.x, h.x, lo.x); split2(v.y, h.y, lo.y);
            split2(v.z, h.z, lo.z); split2(v.w, h.w, lo.w);
            *(ushort4*)&xh[row * 40 + 4 * c4] = h; *(ushort4*)&xl[row * 40 + 4 * c4] = lo;
        }
#pragma unroll
        for (int p = 0; p < 8; ++p) {
            int idx = t + 256 * p, c = idx & 127, kp = idx >> 7, f = k0 + 2 * kp;
            float u0 = 0.f, u1 = 0.f;
            if (f < NF)     u0 = g0 * W0[(size_t)f * ND + c] + g1 * W1[(size_t)f * ND + c];
            if (f + 1 < NF) u1 = g0 * W0[(size_t)(f + 1) * ND + c] + g1 * W1[(size_t)(f + 1) * ND + c];
            unsigned short h0, l0, h1, l1;
            split2(u0, h0, l0); split2(u1, h1, l1);
            *(unsigned int*)&wh[c * 40 + 2 * kp] = (unsigned int)h0 | ((unsigned int)h1 << 16);
            *(unsigned int*)&wl[c * 40 + 2 * kp] = (unsigned int)l0 | ((unsigned int)l1 << 16);
        }
        __syncthreads();
        bf16x8 ah[4], al[4], bh[4], bl[4];
#pragma unroll
        for (int fm = 0; fm < 4; ++fm) {
            int off = (wr * 64 + fm * 16 + (lane & 15)) * 40 + (lane >> 4) * 8;
            ah[fm] = read8b(&xh[off]); al[fm] = read8b(&xl[off]);
        }
#pragma unroll
        for (int fn = 0; fn < 4; ++fn) {
            int off = (wc * 64 + fn * 16 + (lane & 15)) * 40 + (lane >> 4) * 8;
            bh[fn] = read8b(&wh[off]); bl[fn] = read8b(&wl[off]);
        }
#pragma unroll
        for (int fm = 0; fm < 4; ++fm)
#pragma unroll
            for (int fn = 0; fn < 4; ++fn) {
                acc[fm][fn] = __builtin_amdgcn_mfma_f32_16x16x32_bf16(ah[fm], bh[fn], acc[fm][fn], 0, 0, 0);
                acc[fm][fn] = __builtin_amdgcn_mfma_f32_16x16x32_bf16(ah[fm], bl[fn], acc[fm][fn], 0, 0, 0);
                acc[fm][fn] = __builtin_amdgcn_mfma_f32_16x16x32_bf16(al[fm], bh[fn], acc[fm][fn], 0, 0, 0);
            }
        __syncthreads();
    }
#pragma unroll
    for (int fn = 0; fn < 4; ++fn) {
        int col = n0 + wc * 64 + fn * 16 + (lane & 15);
        float bc = g0 * bias[e0 * ND + col] + g1 * bias[e1 * ND + col];
#pragma unroll
        for (int fm = 0; fm < 4; ++fm) {
            int rbase = wr * 64 + fm * 16 + (lane >> 4) * 4;
#pragma unroll
            for (int j = 0; j < 4; ++j)
                out32[((size_t)b * NL + rbase + j) * ND + col] = enc_bf16_hi(acc[fm][fn][j] + bc);
        }
    }
}

extern "C" void kernel_launch(void* const* d_in, const int* in_sizes, int n_in,
                              void* d_out, int out_size, void* d_ws, size_t ws_size,
                              hipStream_t stream) {
    const float* x      = (const float*)d_in[0];
    const float* logits = (const float*)d_in[1];
    const int*   masks  = (const int*)d_in[2];
    const float* W      = (const float*)d_in[3];
    const float* bias   = (const float*)d_in[4];
    unsigned int* out32 = (unsigned int*)d_out;

    int*   eidx = (int*)d_ws;
    float* gval = (float*)((char*)d_ws + 4096);

    gates_kernel<<<dim3(2), dim3(256), 0, stream>>>(logits, masks, eidx, gval);

    if (ws_size >= WT16_OFF + WT16_BYTES) {
        unsigned int* wt16u = (unsigned int*)((char*)d_ws + WT16_OFF);
        wt16_kernel<<<dim3(FP / 32, ND / 32, NE), dim3(256), 0, stream>>>(W, wt16u);
        moe_mfma_h4_kernel<<<dim3(ND / 128, NB), dim3(256), 0, stream>>>(
            x, (const unsigned short*)wt16u, bias, eidx, gval, out32);
    } else {
        moe_mfma_fb_kernel<<<dim3(ND / 128, NB), dim3(256), 0, stream>>>(
            x, W, bias, eidx, gval, out32);
    }
}

// Round 27
// 258.298 us; speedup vs baseline: 5.2034x; 1.2500x over previous
//
#include <hip/hip_runtime.h>
#include <hip/hip_bf16.h>

#define NB 512
#define NL 128
#define NF 900
#define ND 512
#define NE 8
#define FP 928                       // padded K (29 * 32), zero-filled
#define LSTR 36                      // LDS row stride (ushorts) — 18 dwords, gcd(18,32)=2
#define X16_OFF 8192
#define X16_BYTES ((size_t)NB * NL * FP * 2)
#define WT16_OFF (X16_OFF + X16_BYTES)
#define WT16_BYTES ((size_t)NE * ND * FP * 2)

typedef _Float16 f16x8 __attribute__((ext_vector_type(8)));
typedef short bf16x8 __attribute__((ext_vector_type(8)));
typedef float f32x4 __attribute__((ext_vector_type(4)));

// Output encoding (measured R5-R18; R18/R20-R26 PASSED): u32 slots, bf16 in HIGH u16.
static __device__ __forceinline__ unsigned int enc_bf16_hi(float v) {
    unsigned int u = __float_as_uint(v);
    return (u + 0x7FFFu + ((u >> 16) & 1u)) & 0xFFFF0000u;
}
static __device__ __forceinline__ unsigned short bf16r(float v) {
    unsigned int u = __float_as_uint(v);
    return (unsigned short)((u + 0x7FFFu + ((u >> 16) & 1u)) >> 16);
}
static __device__ __forceinline__ float b2f(unsigned short h) {
    return __uint_as_float(((unsigned int)h) << 16);
}
static __device__ __forceinline__ void split2(float v, unsigned short& hi, unsigned short& lo) {
    hi = bf16r(v); lo = bf16r(v - b2f(hi));
}
static __device__ __forceinline__ unsigned short f16b(float v) {
    _Float16 h = (_Float16)v;                      // v_cvt_f16_f32 (RNE)
    return __builtin_bit_cast(unsigned short, h);
}
static __device__ __forceinline__ unsigned int pk16(float a, float b) {
    return (unsigned int)f16b(a) | ((unsigned int)f16b(b) << 16);
}
static __device__ __forceinline__ f16x8 read8h(const unsigned short* p) {
    union { ushort4 u[2]; f16x8 v; } r;
    r.u[0] = *(const ushort4*)(p);
    r.u[1] = *(const ushort4*)(p + 4);
    return r.v;
}
static __device__ __forceinline__ bf16x8 read8b(const unsigned short* p) {
    union { ushort4 u[2]; bf16x8 v; } r;
    r.u[0] = *(const ushort4*)(p);
    r.u[1] = *(const ushort4*)(p + 4);
    return r.v;
}

// ---------------- H0 gates (verified) ----------------
__global__ void gates_kernel(const float* __restrict__ logits,
                             const int* __restrict__ masks,
                             int* __restrict__ eidx,
                             float* __restrict__ gval) {
    int b = blockIdx.x * blockDim.x + threadIdx.x;
    if (b >= NB) return;
    float l[NE], pr[NE], pm[NE];
    int mk[NE];
    float mx = -3.0e38f;
    for (int e = 0; e < NE; ++e) {
        l[e] = logits[b * NE + e];
        mk[e] = masks[b * NE + e];
        mx = fmaxf(mx, l[e]);
    }
    float Z = 0.f;
    for (int e = 0; e < NE; ++e) { pr[e] = expf(l[e] - mx); Z += pr[e]; }
    for (int e = 0; e < NE; ++e) { pr[e] /= Z; pm[e] = (mk[e] == 1) ? pr[e] : 0.f; }
    int i1 = 0;
    for (int e = 1; e < NE; ++e) if (pm[e] > pm[i1]) i1 = e;
    int i2 = (i1 == 0) ? 1 : 0;
    for (int e = 0; e < NE; ++e) if (e != i1 && pm[e] > pm[i2]) i2 = e;
    float v1 = pm[i1], v2 = pm[i2];
    float den = v1 + v2 + 1e-9f;
    eidx[2 * b] = i1; eidx[2 * b + 1] = i2;
    gval[2 * b] = v1 / den; gval[2 * b + 1] = v2 / den;
}

// ---------------- x -> fp16 padded rows, DIV-FREE: 1 block = 1 row ----------------
// 128 threads; thread j handles 8-elem chunk j (116 chunks/row of FP=928).
__global__ __launch_bounds__(128)
void cvt_x_kernel(const float* __restrict__ x, uint4* __restrict__ x16) {
    const int row = blockIdx.x;                  // 0 .. NB*NL-1
    const int j   = threadIdx.x;                 // 0 .. 127
    if (j >= FP / 8) return;
    const int f = 8 * j;
    uint4 pk;
    if (f + 8 <= NF) {                           // chunks 0..111: fully valid
        const float* src = x + (size_t)row * NF + f;
        float4 a = *(const float4*)(src);
        float4 c = *(const float4*)(src + 4);
        pk.x = pk16(a.x, a.y); pk.y = pk16(a.z, a.w);
        pk.z = pk16(c.x, c.y); pk.w = pk16(c.z, c.w);
    } else if (f < NF) {                         // chunk 112: 896..899 valid
        const float* src = x + (size_t)row * NF + f;
        float v[8];
#pragma unroll
        for (int e = 0; e < 8; ++e) v[e] = (f + e < NF) ? src[e] : 0.f;
        pk.x = pk16(v[0], v[1]); pk.y = pk16(v[2], v[3]);
        pk.z = pk16(v[4], v[5]); pk.w = pk16(v[6], v[7]);
    } else {                                     // chunks 113..115: pad
        pk.x = pk.y = pk.z = pk.w = 0u;
    }
    x16[(size_t)row * (FP / 8) + j] = pk;
}

// ---------------- W -> transposed fp16: Wt16[e][d][f], zero-padded ----------------
__global__ void wt16_kernel(const float* __restrict__ W, unsigned int* __restrict__ Wt16) {
    __shared__ float tile[32][33];
    const int e = blockIdx.z, f0 = blockIdx.x * 32, d0 = blockIdx.y * 32;
    const int tx = threadIdx.x & 31, ty = threadIdx.x >> 5;   // 32 x 8
    const float* Wb = W + (size_t)e * NF * ND;
#pragma unroll
    for (int i = 0; i < 4; ++i) {
        int f = f0 + ty + 8 * i;
        tile[ty + 8 * i][tx] = (f < NF) ? Wb[(size_t)f * ND + d0 + tx] : 0.f;
    }
    __syncthreads();
    const int tx2 = threadIdx.x & 15, ty2 = threadIdx.x >> 4;  // 16 x 16
#pragma unroll
    for (int i = 0; i < 2; ++i) {
        int d = d0 + ty2 + 16 * i;
        int f = f0 + 2 * tx2;
        unsigned int pk = pk16(tile[2 * tx2][ty2 + 16 * i], tile[2 * tx2 + 1][ty2 + 16 * i]);
        Wt16[((size_t)e * ND + d) * FP / 2 + f / 2] = pk;
    }
}

// ---------------- fp16 MFMA GEMM: depth-3 reg pipeline, dbuf (R25 verified, 192us) ----------------
struct RegSet { uint4 xa, xb_, w0a, w0b, w1a, w1b; };

__global__ __launch_bounds__(256, 3)
void moe_mfma_h3_kernel(const unsigned short* __restrict__ x16,
                        const unsigned short* __restrict__ Wt16,
                        const float* __restrict__ bias,
                        const int* __restrict__ eidx,
                        const float* __restrict__ gval,
                        unsigned int* __restrict__ out32) {
    __shared__ unsigned short sx[2][128 * LSTR];
    __shared__ unsigned short sw[2][128 * LSTR];

    const int b = blockIdx.y, n0 = blockIdx.x * 128;
    const int t = threadIdx.x, lane = t & 63, wid = t >> 6;
    const int wr = wid >> 1, wc = wid & 1;

    const int e0 = eidx[2 * b], e1 = eidx[2 * b + 1];
    const float g0 = gval[2 * b], g1 = gval[2 * b + 1];
    const _Float16 g0h = (_Float16)g0, g1h = (_Float16)g1;
    f16x8 g08, g18;
#pragma unroll
    for (int i = 0; i < 8; ++i) { g08[i] = g0h; g18[i] = g1h; }

    const unsigned short* xb = x16 + (size_t)b * NL * FP;
    const unsigned short* T0 = Wt16 + ((size_t)e0 * ND + n0) * FP;
    const unsigned short* T1 = Wt16 + ((size_t)e1 * ND + n0) * FP;

    const int row = t >> 1;          // 0..127
    const int hf  = t & 1;           // 16-elem half of the 32-k tile

    f32x4 acc[4][4] = {};
    RegSet Ra, Rb;

#define LOAD_SET(R, tile_)                                                   \
    {                                                                        \
        int f_ = (tile_) * 32 + 16 * hf;                                     \
        (R).xa  = *(const uint4*)(xb + (size_t)row * FP + f_);               \
        (R).xb_ = *(const uint4*)(xb + (size_t)row * FP + f_ + 8);           \
        (R).w0a = *(const uint4*)(T0 + (size_t)row * FP + f_);               \
        (R).w0b = *(const uint4*)(T0 + (size_t)row * FP + f_ + 8);           \
        (R).w1a = *(const uint4*)(T1 + (size_t)row * FP + f_);               \
        (R).w1b = *(const uint4*)(T1 + (size_t)row * FP + f_ + 8);           \
    }

#define WRITE_SET(R, buf_)                                                   \
    {                                                                        \
        int o_ = row * LSTR + 16 * hf;                                       \
        *(uint2*)&sx[buf_][o_]     = make_uint2((R).xa.x, (R).xa.y);         \
        *(uint2*)&sx[buf_][o_ + 4] = make_uint2((R).xa.z, (R).xa.w);         \
        *(uint2*)&sx[buf_][o_ + 8] = make_uint2((R).xb_.x, (R).xb_.y);       \
        *(uint2*)&sx[buf_][o_ +12] = make_uint2((R).xb_.z, (R).xb_.w);       \
        f16x8 w0A = __builtin_bit_cast(f16x8, (R).w0a);                      \
        f16x8 w0B = __builtin_bit_cast(f16x8, (R).w0b);                      \
        f16x8 w1A = __builtin_bit_cast(f16x8, (R).w1a);                      \
        f16x8 w1B = __builtin_bit_cast(f16x8, (R).w1b);                      \
        f16x8 bA = w0A * g08 + w1A * g18;                                    \
        f16x8 bB = w0B * g08 + w1B * g18;                                    \
        uint4 uA = __builtin_bit_cast(uint4, bA);                            \
        uint4 uB = __builtin_bit_cast(uint4, bB);                            \
        *(uint2*)&sw[buf_][o_]     = make_uint2(uA.x, uA.y);                 \
        *(uint2*)&sw[buf_][o_ + 4] = make_uint2(uA.z, uA.w);                 \
        *(uint2*)&sw[buf_][o_ + 8] = make_uint2(uB.x, uB.y);                 \
        *(uint2*)&sw[buf_][o_ +12] = make_uint2(uB.z, uB.w);                 \
    }

    // prologue: tile0 -> LDS[0]; tile1 -> Ra; tile2 -> Rb
    LOAD_SET(Ra, 0)
    WRITE_SET(Ra, 0)
    LOAD_SET(Ra, 1)
    LOAD_SET(Rb, 2)

    int cur = 0;
    for (int s = 0; s < 29; ++s) {
        __syncthreads();             // LDS[cur] = tile s complete; prev reads done
        if (s & 1) {
            if (s < 28) WRITE_SET(Rb, cur ^ 1)      // tile s+1
            if (s < 26) LOAD_SET(Rb, s + 3)
        } else {
            if (s < 28) WRITE_SET(Ra, cur ^ 1)
            if (s < 26) LOAD_SET(Ra, s + 3)
        }
        f16x8 af[4], bf[4];
#pragma unroll
        for (int fm = 0; fm < 4; ++fm) {
            int o = (wr * 64 + fm * 16 + (lane & 15)) * LSTR + (lane >> 4) * 8;
            af[fm] = read8h(&sx[cur][o]);
        }
#pragma unroll
        for (int fn = 0; fn < 4; ++fn) {
            int o = (wc * 64 + fn * 16 + (lane & 15)) * LSTR + (lane >> 4) * 8;
            bf[fn] = read8h(&sw[cur][o]);
        }
#pragma unroll
        for (int fm = 0; fm < 4; ++fm)
#pragma unroll
            for (int fn = 0; fn < 4; ++fn)
                acc[fm][fn] = __builtin_amdgcn_mfma_f32_16x16x32_f16(
                    af[fm], bf[fn], acc[fm][fn], 0, 0, 0);
        cur ^= 1;
    }

    // epilogue (layout verified): D col=lane&15, row=(lane>>4)*4+j
#pragma unroll
    for (int fn = 0; fn < 4; ++fn) {
        int col = n0 + wc * 64 + fn * 16 + (lane & 15);
        float bc = g0 * bias[e0 * ND + col] + g1 * bias[e1 * ND + col];
#pragma unroll
        for (int fm = 0; fm < 4; ++fm) {
            int rbase = wr * 64 + fm * 16 + (lane >> 4) * 4;
#pragma unroll
            for (int j = 0; j < 4; ++j)
                out32[((size_t)b * NL + rbase + j) * ND + col] = enc_bf16_hi(acc[fm][fn][j] + bc);
        }
    }
#undef LOAD_SET
#undef WRITE_SET
}

// ---------------- fallback (R20 kernel, verified) for small ws ----------------
__global__ __launch_bounds__(256)
void moe_mfma_fb_kernel(const float* __restrict__ x, const float* __restrict__ W,
                        const float* __restrict__ bias, const int* __restrict__ eidx,
                        const float* __restrict__ gval, unsigned int* __restrict__ out32) {
    __shared__ unsigned short xh[128 * 40], xl[128 * 40];
    __shared__ unsigned short wh[128 * 40], wl[128 * 40];
    const int b = blockIdx.y, n0 = blockIdx.x * 128;
    const int t = threadIdx.x, lane = t & 63, wid = t >> 6;
    const int wr = wid >> 1, wc = wid & 1;
    const int e0 = eidx[2 * b], e1 = eidx[2 * b + 1];
    const float g0 = gval[2 * b], g1 = gval[2 * b + 1];
    const float* xb = x + (size_t)b * NL * NF;
    const float* W0 = W + (size_t)e0 * NF * ND + n0;
    const float* W1 = W + (size_t)e1 * NF * ND + n0;
    f32x4 acc[4][4] = {};
    for (int k0 = 0; k0 < 928; k0 += 32) {
#pragma unroll
        for (int p = 0; p < 4; ++p) {
            int idx = t + 256 * p, row = idx >> 3, c4 = idx & 7, f = k0 + 4 * c4;
            float4 v; v.x = v.y = v.z = v.w = 0.f;
            if (f + 3 < NF) v = *(const float4*)(xb + (size_t)row * NF + f);
            ushort4 h, lo;
            split2(v.x, h.x, lo.x); split2(v.y, h.y, lo.y);
            split2(v.z, h.z, lo.z); split2(v.w, h.w, lo.w);
            *(ushort4*)&xh[row * 40 + 4 * c4] = h; *(ushort4*)&xl[row * 40 + 4 * c4] = lo;
        }
#pragma unroll
        for (int p = 0; p < 8; ++p) {
            int idx = t + 256 * p, c = idx & 127, kp = idx >> 7, f = k0 + 2 * kp;
            float u0 = 0.f, u1 = 0.f;
            if (f < NF)     u0 = g0 * W0[(size_t)f * ND + c] + g1 * W1[(size_t)f * ND + c];
            if (f + 1 < NF) u1 = g0 * W0[(size_t)(f + 1) * ND + c] + g1 * W1[(size_t)(f + 1) * ND + c];
            unsigned short h0, l0, h1, l1;
            split2(u0, h0, l0); split2(u1, h1, l1);
            *(unsigned int*)&wh[c * 40 + 2 * kp] = (unsigned int)h0 | ((unsigned int)h1 << 16);
            *(unsigned int*)&wl[c * 40 + 2 * kp] = (unsigned int)l0 | ((unsigned int)l1 << 16);
        }
        __syncthreads();
        bf16x8 ah[4], al[4], bh[4], bl[4];
#pragma unroll
        for (int fm = 0; fm < 4; ++fm) {
            int off = (wr * 64 + fm * 16 + (lane & 15)) * 40 + (lane >> 4) * 8;
            ah[fm] = read8b(&xh[off]); al[fm] = read8b(&xl[off]);
        }
#pragma unroll
        for (int fn = 0; fn < 4; ++fn) {
            int off = (wc * 64 + fn * 16 + (lane & 15)) * 40 + (lane >> 4) * 8;
            bh[fn] = read8b(&wh[off]); bl[fn] = read8b(&wl[off]);
        }
#pragma unroll
        for (int fm = 0; fm < 4; ++fm)
#pragma unroll
            for (int fn = 0; fn < 4; ++fn) {
                acc[fm][fn] = __builtin_amdgcn_mfma_f32_16x16x32_bf16(ah[fm], bh[fn], acc[fm][fn], 0, 0, 0);
                acc[fm][fn] = __builtin_amdgcn_mfma_f32_16x16x32_bf16(ah[fm], bl[fn], acc[fm][fn], 0, 0, 0);
                acc[fm][fn] = __builtin_amdgcn_mfma_f32_16x16x32_bf16(al[fm], bh[fn], acc[fm][fn], 0, 0, 0);
            }
        __syncthreads();
    }
#pragma unroll
    for (int fn = 0; fn < 4; ++fn) {
        int col = n0 + wc * 64 + fn * 16 + (lane & 15);
        float bc = g0 * bias[e0 * ND + col] + g1 * bias[e1 * ND + col];
#pragma unroll
        for (int fm = 0; fm < 4; ++fm) {
            int rbase = wr * 64 + fm * 16 + (lane >> 4) * 4;
#pragma unroll
            for (int j = 0; j < 4; ++j)
                out32[((size_t)b * NL + rbase + j) * ND + col] = enc_bf16_hi(acc[fm][fn][j] + bc);
        }
    }
}

extern "C" void kernel_launch(void* const* d_in, const int* in_sizes, int n_in,
                              void* d_out, int out_size, void* d_ws, size_t ws_size,
                              hipStream_t stream) {
    const float* x      = (const float*)d_in[0];
    const float* logits = (const float*)d_in[1];
    const int*   masks  = (const int*)d_in[2];
    const float* W      = (const float*)d_in[3];
    const float* bias   = (const float*)d_in[4];
    unsigned int* out32 = (unsigned int*)d_out;

    int*   eidx = (int*)d_ws;
    float* gval = (float*)((char*)d_ws + 4096);

    gates_kernel<<<dim3(2), dim3(256), 0, stream>>>(logits, masks, eidx, gval);

    if (ws_size >= WT16_OFF + WT16_BYTES) {
        uint4*        x16u4 = (uint4*)((char*)d_ws + X16_OFF);
        unsigned int* wt16u = (unsigned int*)((char*)d_ws + WT16_OFF);
        cvt_x_kernel<<<dim3(NB * NL), dim3(128), 0, stream>>>(x, x16u4);
        wt16_kernel<<<dim3(FP / 32, ND / 32, NE), dim3(256), 0, stream>>>(W, wt16u);
        moe_mfma_h3_kernel<<<dim3(ND / 128, NB), dim3(256), 0, stream>>>(
            (const unsigned short*)x16u4, (const unsigned short*)wt16u,
            bias, eidx, gval, out32);
    } else {
        moe_mfma_fb_kernel<<<dim3(ND / 128, NB), dim3(256), 0, stream>>>(
            x, W, bias, eidx, gval, out32);
    }
}